// Round 17
// baseline (370.463 us; speedup 1.0000x reference)
//
#include <hip/hip_runtime.h>
#include <hip/hip_bf16.h>
#include <math.h>

// ---- problem constants (MultiScaleRetention, B=2,T=2048,E=1024,V=2048,H=8) ----
constexpr int T_SEQ = 2048;
constexpr int BB    = 2;
constexpr int EMBED = 1024;
constexpr int VDIM  = 2048;
constexpr int NHEADS = 8;
constexpr int KDIM  = 128;
constexpr int HDIM  = 256;
constexpr int ROWS  = BB * T_SEQ;  // 4096
constexpr float EPS = 1e-6f;

typedef float  f32x4  __attribute__((ext_vector_type(4)));
typedef __bf16 bf16x8 __attribute__((ext_vector_type(8)));
typedef __bf16 bf16x4 __attribute__((ext_vector_type(4)));

// async global->LDS, 16B per lane. LDS dest is wave-uniform base + lane*16;
// global src is per-lane.
__device__ __forceinline__ void gload16(const void* g, void* l) {
    __builtin_amdgcn_global_load_lds(
        (__attribute__((address_space(1))) void*)g,
        (__attribute__((address_space(3))) void*)l, 16, 0, 0);
}

#define WAITV(n) asm volatile("s_waitcnt vmcnt(" #n ")" ::: "memory")
#define BARRIER() __builtin_amdgcn_s_barrier()

// ============================================================================
// Merged prep: five W[K][N] f32 -> WT[N][K] bf16 transposes (bid < 8192)
// + x f32->bf16 convert (bid >= 8192). One launch.
// ============================================================================
__global__ __launch_bounds__(256)
void prep_all(const float* __restrict__ x, const float* __restrict__ Wq,
              const float* __restrict__ Wk, const float* __restrict__ Wv,
              const float* __restrict__ Wg, const float* __restrict__ Wo,
              __bf16* __restrict__ xb,
              __bf16* __restrict__ WqT, __bf16* __restrict__ WkT,
              __bf16* __restrict__ WvT, __bf16* __restrict__ WgT,
              __bf16* __restrict__ WoT) {
    const int bid = blockIdx.x;
    const int x_ = threadIdx.x, y_ = threadIdx.y;
    if (bid >= 8192) {
        const int i = (bid - 8192) * 256 + y_ * 32 + x_;
        float4 v = reinterpret_cast<const float4*>(x)[i];
        bf16x4 o = { (__bf16)v.x, (__bf16)v.y, (__bf16)v.z, (__bf16)v.w };
        reinterpret_cast<bf16x4*>(xb)[i] = o;
        return;
    }
    const float* W; __bf16* WT; int K, N, cx, cy;
    if (bid < 1024)      { W = Wq; WT = WqT; K = 1024; N = 1024; int rm = bid;        cx = rm & 31; cy = rm >> 5; }
    else if (bid < 2048) { W = Wk; WT = WkT; K = 1024; N = 1024; int rm = bid - 1024; cx = rm & 31; cy = rm >> 5; }
    else if (bid < 4096) { W = Wv; WT = WvT; K = 1024; N = 2048; int rm = bid - 2048; cx = rm & 63; cy = rm >> 6; }
    else if (bid < 6144) { W = Wg; WT = WgT; K = 1024; N = 2048; int rm = bid - 4096; cx = rm & 63; cy = rm >> 6; }
    else                 { W = Wo; WT = WoT; K = 2048; N = 1024; int rm = bid - 6144; cx = rm & 31; cy = rm >> 5; }

    __shared__ float tile[32][33];
    const int c0 = cx * 32, k0 = cy * 32;
    #pragma unroll
    for (int p = 0; p < 4; ++p)
        tile[y_ + p * 8][x_] = W[(size_t)(k0 + y_ + p * 8) * N + c0 + x_];
    __syncthreads();
    #pragma unroll
    for (int p = 0; p < 4; ++p)
        WT[(size_t)(c0 + y_ + p * 8) * K + k0 + x_] = (__bf16)tile[x_][y_ + p * 8];
}

// ============================================================================
// Kernel B: Q|K projection GEMM (2-barrier m97, 128x128, BK=64, G4 swizzle).
// RoPE + kscale in epilogue. Grid 512 = 2/CU; XCD col-pinning. (Unchanged.)
// ============================================================================
__global__ __launch_bounds__(256)
void gemm_qk(const __bf16* __restrict__ A, const __bf16* __restrict__ BT,
             __bf16* __restrict__ Qb, __bf16* __restrict__ Kb,
             const float* __restrict__ sinT, const float* __restrict__ cosT) {
    constexpr int K = EMBED;
    __shared__ __align__(16) char smem[32768];
    __bf16* As = (__bf16*)smem;               // [128][64] linear, swizzled
    __bf16* Bs = (__bf16*)(smem + 16384);     // [128][64] linear, swizzled

    const int bid = blockIdx.x;
    const int rr = bid >> 3;                  // 0..63
    const int bx = (bid & 7) * 2 + (rr & 1);  // 0..15 (2 cols per XCD)
    const int by = rr >> 1;                   // 0..31
    const int rowBase = by * 128;
    const int colBase = bx * 128;

    const int tid = threadIdx.x;
    const int w = tid >> 6, lane = tid & 63;
    const int g = lane >> 4, r = lane & 15;
    const int wm = w >> 1, wn = w & 1;

    const int vr  = lane >> 3;
    const int swz = ((lane & 7) ^ vr) * 8;
    const __bf16* aSb = A  + (size_t)(rowBase + 32 * w + vr) * K + swz;
    const __bf16* bSb = BT + (size_t)(colBase + 32 * w + vr) * K + swz;

    f32x4 acc[4][4];
    #pragma unroll
    for (int i = 0; i < 4; ++i)
        #pragma unroll
        for (int j = 0; j < 4; ++j)
            acc[i][j] = (f32x4){0.f, 0.f, 0.f, 0.f};

    for (int k0 = 0; k0 < K; k0 += 64) {
        __syncthreads();
        #pragma unroll
        for (int p = 0; p < 4; ++p) {
            const int cc = 4 * w + p;
            gload16(aSb + (size_t)(8 * p) * K + k0, smem         + cc * 1024);
            gload16(bSb + (size_t)(8 * p) * K + k0, smem + 16384 + cc * 1024);
        }
        __syncthreads();

        #pragma unroll
        for (int kk = 0; kk < 2; ++kk) {
            bf16x8 bfrag[4];
            #pragma unroll
            for (int nf = 0; nf < 4; ++nf) {
                const int row = wn * 64 + nf * 16 + r;
                bfrag[nf] = *reinterpret_cast<const bf16x8*>(
                    &Bs[row * 64 + (((kk << 2) + g) ^ (r & 7)) * 8]);
            }
            #pragma unroll
            for (int mf = 0; mf < 4; ++mf) {
                const int row = wm * 64 + mf * 16 + r;
                bf16x8 a = *reinterpret_cast<const bf16x8*>(
                    &As[row * 64 + (((kk << 2) + g) ^ (r & 7)) * 8]);
                #pragma unroll
                for (int nf = 0; nf < 4; ++nf)
                    acc[mf][nf] = __builtin_amdgcn_mfma_f32_16x16x32_bf16(a, bfrag[nf], acc[mf][nf], 0, 0, 0);
            }
        }
    }

    constexpr float kscale = 0.08838834764831845f;  // KEY_DIM^-0.5
    __bf16* dst; int cofs; float alphaSeg;
    if (colBase < 1024) { dst = Qb; cofs = colBase;        alphaSeg = 1.0f;   }
    else                { dst = Kb; cofs = colBase - 1024; alphaSeg = kscale; }

    #pragma unroll
    for (int mf = 0; mf < 4; ++mf)
        #pragma unroll
        for (int nf = 0; nf < 4; ++nf)
            #pragma unroll
            for (int j = 0; j < 4; ++j) {
                const int row  = rowBase + wm * 64 + mf * 16 + g * 4 + j;
                const int colL = cofs + wn * 64 + nf * 16 + r;
                float v = acc[mf][nf][j] * alphaSeg;
                const float p = __shfl_xor(v, 1);
                const int t  = row & (T_SEQ - 1);
                const int dh = colL & (KDIM - 1);
                const float c = cosT[t * KDIM + dh];
                const float s = sinT[t * KDIM + dh];
                v = (r & 1) ? (v * c + p * s) : (v * c - p * s);
                dst[(size_t)row * 1024 + colL] = (__bf16)v;
            }
}

// ============================================================================
// Kernel A: V|G projection GEMM — 256x256 8-PHASE, grid 256 = 1/CU.
// (Unchanged from R14.)
// ============================================================================
#define STAGEH(ISB, TAU, HF) do { \
    const __bf16* s_ = ((ISB) ? BT : A) + \
        (size_t)((((ISB) ? colBase : rowBase)) + (HF) * 128 + w * 8 + srow) * 1024 + \
        (TAU) * 64 + swz; \
    char* d_ = smem + ((ISB) ? 65536 : 0) + (((TAU) & 1) * 2 + (HF)) * 16384 + w * 1024; \
    gload16(s_, d_); \
    gload16(s_ + (size_t)64 * 1024, d_ + 8192); \
} while (0)

#define QPHASE(TAU, Q, STGSTMT) do { \
    const int p_ = (TAU) & 1; \
    const __bf16* Ab_ = (const __bf16*)(smem + (p_ * 2 + wm) * 16384); \
    const __bf16* Bb_ = (const __bf16*)(smem + 65536 + (p_ * 2 + bh) * 16384); \
    if ((Q) == 0) { \
        _Pragma("unroll") for (int nf = 0; nf < 4; ++nf) \
        _Pragma("unroll") for (int kk = 0; kk < 2; ++kk) \
            bq[nf][kk] = *(const bf16x8*)(Bb_ + (bro + nf * 16) * 64 + ((kk * 4 + g) ^ rx) * 8); \
    } \
    bf16x8 aq_[2][2]; \
    _Pragma("unroll") for (int i = 0; i < 2; ++i) \
    _Pragma("unroll") for (int kk = 0; kk < 2; ++kk) \
        aq_[i][kk] = *(const bf16x8*)(Ab_ + (((Q) * 2 + i) * 16 + r) * 64 + ((kk * 4 + g) ^ rx) * 8); \
    STGSTMT; \
    BARRIER(); \
    __builtin_amdgcn_s_setprio(1); \
    _Pragma("unroll") for (int i = 0; i < 2; ++i) \
    _Pragma("unroll") for (int nf = 0; nf < 4; ++nf) \
    _Pragma("unroll") for (int kk = 0; kk < 2; ++kk) \
        acc[(Q) * 2 + i][nf] = __builtin_amdgcn_mfma_f32_16x16x32_bf16( \
            aq_[i][kk], bq[nf][kk], acc[(Q) * 2 + i][nf], 0, 0, 0); \
    __builtin_amdgcn_s_setprio(0); \
} while (0)

__global__ __launch_bounds__(512, 2)
void gemm_vg(const __bf16* __restrict__ A, const __bf16* __restrict__ BT,
             __bf16* __restrict__ Vt, __bf16* __restrict__ Gb) {
    __shared__ __align__(16) char smem[131072];

    const int bid = blockIdx.x;
    const int j2 = bid >> 3;                    // 0..31
    const int bxA = (bid & 7) * 2 + (j2 & 1);   // 0..15
    const int by  = j2 >> 1;                    // 0..15
    const int rowBase = by * 256;
    const int colBase = 2048 + bxA * 256;       // packed-WT row offset

    const int tid = threadIdx.x;
    const int w = tid >> 6, lane = tid & 63;
    const int g = lane >> 4, r = lane & 15;
    const int wm = w >> 2, wn = w & 3;
    const int rx = r & 7;
    const int bh = wn >> 1;
    const int bro = (wn & 1) * 64 + r;

    const int srow = lane >> 3;
    const int swz  = ((lane & 7) ^ srow) * 8;

    f32x4 acc[8][4];
    #pragma unroll
    for (int i = 0; i < 8; ++i)
        #pragma unroll
        for (int j = 0; j < 4; ++j)
            acc[i][j] = (f32x4){0.f, 0.f, 0.f, 0.f};
    bf16x8 bq[4][2];

    STAGEH(1, 0, 0); STAGEH(1, 0, 1);
    STAGEH(0, 0, 0); STAGEH(0, 0, 1);
    STAGEH(1, 1, 0); STAGEH(1, 1, 1);
    WAITV(4);
    BARRIER();

    for (int it = 0; it < 8; ++it) {
        const int e = 2 * it, o = e + 1;
        const bool more = (it < 7);
        QPHASE(e, 0, STAGEH(0, o, 0));                        BARRIER();
        QPHASE(e, 1, STAGEH(0, o, 1));                        BARRIER();
        QPHASE(e, 2, if (more) STAGEH(1, e + 2, 0));          BARRIER();
        QPHASE(e, 3, if (more) STAGEH(1, e + 2, 1));
        if (more) { WAITV(4); } else { WAITV(0); }            BARRIER();
        QPHASE(o, 0, if (more) STAGEH(0, e + 2, 0));          BARRIER();
        QPHASE(o, 1, if (more) STAGEH(0, e + 2, 1));          BARRIER();
        QPHASE(o, 2, if (more) STAGEH(1, o + 2, 0));          BARRIER();
        QPHASE(o, 3, if (more) STAGEH(1, o + 2, 1));
        if (more) { WAITV(4); } else { WAITV(0); }            BARRIER();
    }

    if (bxA < 8) {
        // V segment: transposed write to Vt[b][h][d][t]
        __bf16* Es = (__bf16*)smem + w * 4608;
        const int colV0 = (colBase - 2048) + wn * 64;
        const int h = colV0 >> 8, dd0 = colV0 & 255;
        const int li = lane & 7, rgrp = lane >> 3;
        #pragma unroll
        for (int h2 = 0; h2 < 2; ++h2) {
            #pragma unroll
            for (int mf = 0; mf < 4; ++mf)
                #pragma unroll
                for (int nf = 0; nf < 4; ++nf) {
                    f32x4 a = acc[h2 * 4 + mf][nf];
                    bf16x4 v = { (__bf16)a[0], (__bf16)a[1], (__bf16)a[2], (__bf16)a[3] };
                    *reinterpret_cast<bf16x4*>(&Es[(nf * 16 + r) * 72 + mf * 16 + g * 4]) = v;
                }
            __syncthreads();
            const int t0g = rowBase + wm * 128 + h2 * 64;
            const int bq_ = t0g >> 11, tl = t0g & 2047;
            __bf16* vtb = Vt + ((size_t)(bq_ * NHEADS + h) * HDIM + dd0) * T_SEQ + tl;
            #pragma unroll
            for (int c = 0; c < 8; ++c) {
                const int drow = 8 * c + rgrp;
                bf16x8 v = *reinterpret_cast<const bf16x8*>(&Es[drow * 72 + li * 8]);
                *reinterpret_cast<bf16x8*>(vtb + (size_t)drow * T_SEQ + li * 8) = v;
            }
            __syncthreads();
        }
        return;
    }

    const int cofs = colBase - 4096;
    #pragma unroll
    for (int mf = 0; mf < 8; ++mf)
        #pragma unroll
        for (int nf = 0; nf < 4; ++nf)
            #pragma unroll
            for (int j = 0; j < 4; ++j) {
                const int row  = rowBase + wm * 128 + mf * 16 + g * 4 + j;
                const int colL = cofs + wn * 64 + nf * 16 + r;
                Gb[(size_t)row * 2048 + colL] = (__bf16)acc[mf][nf][j];
            }
}

// ============================================================================
// Output projection: 64x128 tile, BK=64, 2-barrier, XCD swizzle. (Unchanged.)
// ============================================================================
__global__ __launch_bounds__(256)
void gemm_wo(const __bf16* __restrict__ A, const __bf16* __restrict__ BT,
             float* __restrict__ C) {
    constexpr int N = EMBED, K = VDIM;
    __shared__ __align__(16) char smem[24576];
    __bf16* As = (__bf16*)smem;               // [64][64]
    __bf16* Bs = (__bf16*)(smem + 8192);      // [128][64]

    const int bid = blockIdx.x;
    const int swzb = (bid & 7) * 64 + (bid >> 3);
    const int rowBase = (swzb >> 3) * 64;
    const int colBase = (swzb & 7) * 128;

    const int tid = threadIdx.x;
    const int w = tid >> 6, lane = tid & 63;
    const int g = lane >> 4, r = lane & 15;
    const int wm = w >> 1, wn = w & 1;

    const int vr  = lane >> 3;
    const int swz = ((lane & 7) ^ vr) * 8;
    const __bf16* aSb = A  + (size_t)(rowBase + 16 * w + vr) * K + swz;
    const __bf16* bSb = BT + (size_t)(colBase + 32 * w + vr) * K + swz;

    f32x4 acc[2][4];
    #pragma unroll
    for (int i = 0; i < 2; ++i)
        #pragma unroll
        for (int j = 0; j < 4; ++j)
            acc[i][j] = (f32x4){0.f, 0.f, 0.f, 0.f};

    for (int k0 = 0; k0 < K; k0 += 64) {
        __syncthreads();
        #pragma unroll
        for (int p = 0; p < 2; ++p) {
            const int cc = 2 * w + p;
            gload16(aSb + (size_t)(8 * p) * K + k0, smem + cc * 1024);
        }
        #pragma unroll
        for (int p = 0; p < 4; ++p) {
            const int cc = 4 * w + p;
            gload16(bSb + (size_t)(8 * p) * K + k0, smem + 8192 + cc * 1024);
        }
        __syncthreads();

        #pragma unroll
        for (int kk = 0; kk < 2; ++kk) {
            bf16x8 bfrag[4];
            #pragma unroll
            for (int nf = 0; nf < 4; ++nf) {
                const int row = wn * 64 + nf * 16 + r;
                bfrag[nf] = *reinterpret_cast<const bf16x8*>(
                    &Bs[row * 64 + (((kk << 2) + g) ^ (r & 7)) * 8]);
            }
            #pragma unroll
            for (int mf = 0; mf < 2; ++mf) {
                const int row = wm * 32 + mf * 16 + r;
                bf16x8 a = *reinterpret_cast<const bf16x8*>(
                    &As[row * 64 + (((kk << 2) + g) ^ (r & 7)) * 8]);
                #pragma unroll
                for (int nf = 0; nf < 4; ++nf)
                    acc[mf][nf] = __builtin_amdgcn_mfma_f32_16x16x32_bf16(a, bfrag[nf], acc[mf][nf], 0, 0, 0);
            }
        }
    }

    #pragma unroll
    for (int mf = 0; mf < 2; ++mf)
        #pragma unroll
        for (int nf = 0; nf < 4; ++nf)
            #pragma unroll
            for (int j = 0; j < 4; ++j) {
                const int row = rowBase + wm * 32 + mf * 16 + g * 4 + j;
                const int col = colBase + wn * 64 + nf * 16 + r;
                C[(size_t)row * N + col] = acc[mf][nf][j];
            }
}

// ============================================================================
// MFMA retention — NO K/V LDS STAGING (m169: don't stage what L2 fits).
// Per-(b,h) K/V = 1.5MB, XCD-pinned (h=bid&7) -> L2-resident. K and V MFMA
// fragments are 16B-contiguous per lane in Kb / Vt -> read DIRECTLY from
// global. LDS holds only the per-wave P turn (9.2KB). DS ops of a single
// wave execute in program order -> wave-local Ps needs NO barrier; the whole
// kernel is barrier-free and waves run independently (VGPR-capped occupancy
// ~3x the old LDS-capped 8 waves/CU; per-tile L2/VALU latency hidden by TLP).
// R14 mapping: slot=bid>>3, b=slot&1, x=slot>>1, qt = b==0 ? 31-x : x.
// ============================================================================
__global__ __launch_bounds__(256)
void retention_mfma(const __bf16* __restrict__ Qb, const __bf16* __restrict__ Kb,
                    const __bf16* __restrict__ Vt,
                    const __bf16* __restrict__ Gb, __bf16* __restrict__ Yb) {
    const int tid = threadIdx.x;
    const int w = tid >> 6, lane = tid & 63;
    const int g = lane >> 4, r = lane & 15;
    const int bid = blockIdx.x;
    const int h = bid & 7;
    const int slot = bid >> 3;
    const int b = slot & 1;
    const int x = slot >> 1;
    const int qt = (b == 0) ? (31 - x) : x;
    const int tt0 = qt * 64;
    const int trow0 = w * 16;

    __shared__ __align__(16) __bf16 Ps[4][16][72];  // per-wave P tile, +8 pad

    // ---- decay constants (mask on the fly) ----
    const float rho   = 1.0f - exp2f(-(float)(5 + h));
    const float l2r   = log2f(rho);
    const float inv1m = exp2f((float)(5 + h));      // 1/(1-rho)
    int   tj[4];
    float nrm[4];
    #pragma unroll
    for (int j = 0; j < 4; ++j) {
        tj[j] = tt0 + trow0 + g * 4 + j;
        nrm[j] = rsqrtf((1.0f - exp2f(l2r * (float)(tj[j] + 1))) * inv1m);
    }
    float pneg[4];                                  // rho^(-(ssub*16+r))
    #pragma unroll
    for (int ssub = 0; ssub < 4; ++ssub)
        pneg[ssub] = exp2f(-l2r * (float)(ssub * 16 + r));

    // Q fragments: wave's 16 q-rows x 128 k, persistent in registers
    bf16x8 qf[4];
    {
        const __bf16* qrow = Qb + ((size_t)(b * T_SEQ + tt0 + trow0 + r)) * EMBED + h * KDIM;
        #pragma unroll
        for (int kb = 0; kb < 4; ++kb)
            qf[kb] = *reinterpret_cast<const bf16x8*>(qrow + kb * 32 + g * 8);
    }

    f32x4 acc[16];
    #pragma unroll
    for (int db = 0; db < 16; ++db) acc[db] = (f32x4){0.f, 0.f, 0.f, 0.f};
    float dsum[4] = {0.f, 0.f, 0.f, 0.f};

    // direct-L2 fragment bases (per-lane, 16B-contiguous loads)
    const __bf16* kfb = Kb + ((size_t)(b * T_SEQ + r)) * EMBED + h * KDIM + g * 8;
    const __bf16* vfb = Vt + ((size_t)((b * NHEADS + h) * HDIM) + r) * T_SEQ + g * 8;

    const int nS = qt + 1;
    for (int st = 0; st < nS; ++st) {
        const int ss0 = st * 64;

        // per-tile decay factors
        float wj[4];
        #pragma unroll
        for (int j = 0; j < 4; ++j)
            wj[j] = exp2f(l2r * (float)(tj[j] - ss0)) * nrm[j];
        const bool diag = (st == qt);

        // ---- QK^T: K fragments straight from L2 ----
        #pragma unroll
        for (int ssub = 0; ssub < 4; ++ssub) {
            f32x4 sacc = (f32x4){0.f, 0.f, 0.f, 0.f};
            #pragma unroll
            for (int kb = 0; kb < 4; ++kb) {
                bf16x8 kf = *reinterpret_cast<const bf16x8*>(
                    kfb + (size_t)(ss0 + ssub * 16) * EMBED + kb * 32);
                sacc = __builtin_amdgcn_mfma_f32_16x16x32_bf16(qf[kb], kf, sacc, 0, 0, 0);
            }
            const int scol = ss0 + ssub * 16 + r;
            const float mfac = pneg[ssub];
            #pragma unroll
            for (int j = 0; j < 4; ++j) {
                float pv = sacc[j] * (wj[j] * mfac);
                if (diag && scol > tj[j]) pv = 0.f;
                dsum[j] += fabsf(pv);
                Ps[w][g * 4 + j][ssub * 16 + r] = (__bf16)pv;
            }
        }

        // ---- PV: V fragments straight from L2; Ps turn is wave-local ----
        #pragma unroll
        for (int sh = 0; sh < 2; ++sh) {
            bf16x8 pf = *reinterpret_cast<const bf16x8*>(&Ps[w][r][sh * 32 + g * 8]);
            #pragma unroll
            for (int db = 0; db < 16; ++db) {
                bf16x8 vf = *reinterpret_cast<const bf16x8*>(
                    vfb + (size_t)(db * 16) * T_SEQ + ss0 + sh * 32);
                acc[db] = __builtin_amdgcn_mfma_f32_16x16x32_bf16(pf, vf, acc[db], 0, 0, 0);
            }
        }
    }

    // ---- epilogue ----
    #pragma unroll
    for (int j = 0; j < 4; ++j) {
        float v = dsum[j];
        v += __shfl_xor(v, 1); v += __shfl_xor(v, 2);
        v += __shfl_xor(v, 4); v += __shfl_xor(v, 8);
        dsum[j] = fminf(fmaxf(v, 1.0f), 50000.0f);
    }
    float ss[4] = {0.f, 0.f, 0.f, 0.f};
    #pragma unroll
    for (int db = 0; db < 16; ++db)
        #pragma unroll
        for (int j = 0; j < 4; ++j) {
            const float v = acc[db][j] / dsum[j];
            acc[db][j] = v;
            ss[j] = fmaf(v, v, ss[j]);
        }
    #pragma unroll
    for (int j = 0; j < 4; ++j) {
        float v = ss[j];
        v += __shfl_xor(v, 1); v += __shfl_xor(v, 2);
        v += __shfl_xor(v, 4); v += __shfl_xor(v, 8);
        ss[j] = rsqrtf(v * (1.0f / 256.0f) + EPS);
    }
    #pragma unroll
    for (int j = 0; j < 4; ++j) {
        const size_t row = (size_t)(b * T_SEQ + tj[j]);
        const __bf16* grow = Gb + row * VDIM + h * HDIM;
        __bf16* yrow = Yb + row * VDIM + h * HDIM;
        #pragma unroll
        for (int db = 0; db < 16; ++db) {
            const int c = db * 16 + r;
            const float gv = (float)grow[c];
            const float sil = gv / (1.0f + expf(-gv));
            yrow[c] = (__bf16)(sil * acc[db][j] * ss[j]);
        }
    }
}

// ============================================================================
// launch
// ============================================================================
extern "C" void kernel_launch(void* const* d_in, const int* in_sizes, int n_in,
                              void* d_out, int out_size, void* d_ws, size_t ws_size,
                              hipStream_t stream) {
    (void)in_sizes; (void)n_in; (void)out_size; (void)ws_size;

    const float* x    = (const float*)d_in[0];
    const float* sinT = (const float*)d_in[1];
    const float* cosT = (const float*)d_in[2];
    // d_in[3] (mask) is recomputed on the fly in retention_mfma
    const float* Wq   = (const float*)d_in[4];
    const float* Wk   = (const float*)d_in[5];
    const float* Wv   = (const float*)d_in[6];
    const float* Wg   = (const float*)d_in[7];
    const float* Wo   = (const float*)d_in[8];
    float* out = (float*)d_out;

    // workspace layout (bytes). WqT..WgT contiguous -> packed [6144][1024].
    char* wsp = (char*)d_ws;
    __bf16* xb  = (__bf16*)(wsp);
    __bf16* WqT = (__bf16*)(wsp + (8u  << 20));
    __bf16* WkT = (__bf16*)(wsp + (10u << 20));
    __bf16* WvT = (__bf16*)(wsp + (12u << 20));
    __bf16* WgT = (__bf16*)(wsp + (16u << 20));
    __bf16* WoT = (__bf16*)(wsp + (20u << 20));
    __bf16* Qb  = (__bf16*)(wsp + (24u << 20));
    __bf16* Kb  = (__bf16*)(wsp + (32u << 20));
    __bf16* Yb  = (__bf16*)(wsp + (40u << 20));  // retention output (gated)
    __bf16* Gb  = (__bf16*)(wsp + (56u << 20));
    __bf16* Vt  = (__bf16*)(wsp + (72u << 20));
    __bf16* WTall = WqT;                         // packed Q|K|V|G weights

    const dim3 blk(256);
    const dim3 tblk(32, 8);

    // ---- prep (merged transposes + x convert) ----
    prep_all<<<12288, tblk, 0, stream>>>(x, Wq, Wk, Wv, Wg, Wo,
                                         xb, WqT, WkT, WvT, WgT, WoT);

    // ---- Q|K projection (proven 2-barrier 128^2; RoPE + kscale) ----
    gemm_qk<<<512, blk, 0, stream>>>(xb, WTall, Qb, Kb, sinT, cosT);

    // ---- V|G projection (8-phase 256^2, grid = exactly 1/CU) ----
    gemm_vg<<<256, 512, 0, stream>>>(xb, WTall, Vt, Gb);

    // ---- fused retention (barrier-free, direct-L2 K/V fragments) ----
    retention_mfma<<<512, blk, 0, stream>>>(Qb, Kb, Vt, Gb, Yb);

    // ---- output projection ----
    gemm_wo<<<512, blk, 0, stream>>>(Yb, WoT, out);
}

// Round 18
// 172.148 us; speedup vs baseline: 2.1520x; 2.1520x over previous
//
#include <hip/hip_runtime.h>
#include <hip/hip_bf16.h>
#include <math.h>

// ---- problem constants (MultiScaleRetention, B=2,T=2048,E=1024,V=2048,H=8) ----
constexpr int T_SEQ = 2048;
constexpr int BB    = 2;
constexpr int EMBED = 1024;
constexpr int VDIM  = 2048;
constexpr int NHEADS = 8;
constexpr int KDIM  = 128;
constexpr int HDIM  = 256;
constexpr int ROWS  = BB * T_SEQ;  // 4096
constexpr float EPS = 1e-6f;

typedef float  f32x4  __attribute__((ext_vector_type(4)));
typedef __bf16 bf16x8 __attribute__((ext_vector_type(8)));
typedef __bf16 bf16x4 __attribute__((ext_vector_type(4)));

// async global->LDS, 16B per lane. LDS dest is wave-uniform base + lane*16;
// global src is per-lane.
__device__ __forceinline__ void gload16(const void* g, void* l) {
    __builtin_amdgcn_global_load_lds(
        (__attribute__((address_space(1))) void*)g,
        (__attribute__((address_space(3))) void*)l, 16, 0, 0);
}

#define WAITV(n) asm volatile("s_waitcnt vmcnt(" #n ")" ::: "memory")
#define BARRIER() __builtin_amdgcn_s_barrier()

// ============================================================================
// Merged prep: five W[K][N] f32 -> WT[N][K] bf16 transposes (bid < 8192)
// + x f32->bf16 convert (bid >= 8192). One launch.
// ============================================================================
__global__ __launch_bounds__(256)
void prep_all(const float* __restrict__ x, const float* __restrict__ Wq,
              const float* __restrict__ Wk, const float* __restrict__ Wv,
              const float* __restrict__ Wg, const float* __restrict__ Wo,
              __bf16* __restrict__ xb,
              __bf16* __restrict__ WqT, __bf16* __restrict__ WkT,
              __bf16* __restrict__ WvT, __bf16* __restrict__ WgT,
              __bf16* __restrict__ WoT) {
    const int bid = blockIdx.x;
    const int x_ = threadIdx.x, y_ = threadIdx.y;
    if (bid >= 8192) {
        const int i = (bid - 8192) * 256 + y_ * 32 + x_;
        float4 v = reinterpret_cast<const float4*>(x)[i];
        bf16x4 o = { (__bf16)v.x, (__bf16)v.y, (__bf16)v.z, (__bf16)v.w };
        reinterpret_cast<bf16x4*>(xb)[i] = o;
        return;
    }
    const float* W; __bf16* WT; int K, N, cx, cy;
    if (bid < 1024)      { W = Wq; WT = WqT; K = 1024; N = 1024; int rm = bid;        cx = rm & 31; cy = rm >> 5; }
    else if (bid < 2048) { W = Wk; WT = WkT; K = 1024; N = 1024; int rm = bid - 1024; cx = rm & 31; cy = rm >> 5; }
    else if (bid < 4096) { W = Wv; WT = WvT; K = 1024; N = 2048; int rm = bid - 2048; cx = rm & 63; cy = rm >> 6; }
    else if (bid < 6144) { W = Wg; WT = WgT; K = 1024; N = 2048; int rm = bid - 4096; cx = rm & 63; cy = rm >> 6; }
    else                 { W = Wo; WT = WoT; K = 2048; N = 1024; int rm = bid - 6144; cx = rm & 31; cy = rm >> 5; }

    __shared__ float tile[32][33];
    const int c0 = cx * 32, k0 = cy * 32;
    #pragma unroll
    for (int p = 0; p < 4; ++p)
        tile[y_ + p * 8][x_] = W[(size_t)(k0 + y_ + p * 8) * N + c0 + x_];
    __syncthreads();
    #pragma unroll
    for (int p = 0; p < 4; ++p)
        WT[(size_t)(c0 + y_ + p * 8) * K + k0 + x_] = (__bf16)tile[x_][y_ + p * 8];
}

// ============================================================================
// Kernel B: Q|K projection GEMM (2-barrier m97, 128x128, BK=64, G4 swizzle).
// RoPE + kscale in epilogue. Grid 512 = 2/CU; XCD col-pinning.
// ============================================================================
__global__ __launch_bounds__(256)
void gemm_qk(const __bf16* __restrict__ A, const __bf16* __restrict__ BT,
             __bf16* __restrict__ Qb, __bf16* __restrict__ Kb,
             const float* __restrict__ sinT, const float* __restrict__ cosT) {
    constexpr int K = EMBED;
    __shared__ __align__(16) char smem[32768];
    __bf16* As = (__bf16*)smem;               // [128][64] linear, swizzled
    __bf16* Bs = (__bf16*)(smem + 16384);     // [128][64] linear, swizzled

    const int bid = blockIdx.x;
    const int rr = bid >> 3;                  // 0..63
    const int bx = (bid & 7) * 2 + (rr & 1);  // 0..15 (2 cols per XCD)
    const int by = rr >> 1;                   // 0..31
    const int rowBase = by * 128;
    const int colBase = bx * 128;

    const int tid = threadIdx.x;
    const int w = tid >> 6, lane = tid & 63;
    const int g = lane >> 4, r = lane & 15;
    const int wm = w >> 1, wn = w & 1;

    const int vr  = lane >> 3;
    const int swz = ((lane & 7) ^ vr) * 8;
    const __bf16* aSb = A  + (size_t)(rowBase + 32 * w + vr) * K + swz;
    const __bf16* bSb = BT + (size_t)(colBase + 32 * w + vr) * K + swz;

    f32x4 acc[4][4];
    #pragma unroll
    for (int i = 0; i < 4; ++i)
        #pragma unroll
        for (int j = 0; j < 4; ++j)
            acc[i][j] = (f32x4){0.f, 0.f, 0.f, 0.f};

    for (int k0 = 0; k0 < K; k0 += 64) {
        __syncthreads();
        #pragma unroll
        for (int p = 0; p < 4; ++p) {
            const int cc = 4 * w + p;
            gload16(aSb + (size_t)(8 * p) * K + k0, smem         + cc * 1024);
            gload16(bSb + (size_t)(8 * p) * K + k0, smem + 16384 + cc * 1024);
        }
        __syncthreads();

        #pragma unroll
        for (int kk = 0; kk < 2; ++kk) {
            bf16x8 bfrag[4];
            #pragma unroll
            for (int nf = 0; nf < 4; ++nf) {
                const int row = wn * 64 + nf * 16 + r;
                bfrag[nf] = *reinterpret_cast<const bf16x8*>(
                    &Bs[row * 64 + (((kk << 2) + g) ^ (r & 7)) * 8]);
            }
            #pragma unroll
            for (int mf = 0; mf < 4; ++mf) {
                const int row = wm * 64 + mf * 16 + r;
                bf16x8 a = *reinterpret_cast<const bf16x8*>(
                    &As[row * 64 + (((kk << 2) + g) ^ (r & 7)) * 8]);
                #pragma unroll
                for (int nf = 0; nf < 4; ++nf)
                    acc[mf][nf] = __builtin_amdgcn_mfma_f32_16x16x32_bf16(a, bfrag[nf], acc[mf][nf], 0, 0, 0);
            }
        }
    }

    constexpr float kscale = 0.08838834764831845f;  // KEY_DIM^-0.5
    __bf16* dst; int cofs; float alphaSeg;
    if (colBase < 1024) { dst = Qb; cofs = colBase;        alphaSeg = 1.0f;   }
    else                { dst = Kb; cofs = colBase - 1024; alphaSeg = kscale; }

    #pragma unroll
    for (int mf = 0; mf < 4; ++mf)
        #pragma unroll
        for (int nf = 0; nf < 4; ++nf)
            #pragma unroll
            for (int j = 0; j < 4; ++j) {
                const int row  = rowBase + wm * 64 + mf * 16 + g * 4 + j;
                const int colL = cofs + wn * 64 + nf * 16 + r;
                float v = acc[mf][nf][j] * alphaSeg;
                const float p = __shfl_xor(v, 1);
                const int t  = row & (T_SEQ - 1);
                const int dh = colL & (KDIM - 1);
                const float c = cosT[t * KDIM + dh];
                const float s = sinT[t * KDIM + dh];
                v = (r & 1) ? (v * c + p * s) : (v * c - p * s);
                dst[(size_t)row * 1024 + colL] = (__bf16)v;
            }
}

// ============================================================================
// Kernel A: V|G projection GEMM — 256x256 8-PHASE, grid 256 = 1/CU.
// ============================================================================
#define STAGEH(ISB, TAU, HF) do { \
    const __bf16* s_ = ((ISB) ? BT : A) + \
        (size_t)((((ISB) ? colBase : rowBase)) + (HF) * 128 + w * 8 + srow) * 1024 + \
        (TAU) * 64 + swz; \
    char* d_ = smem + ((ISB) ? 65536 : 0) + (((TAU) & 1) * 2 + (HF)) * 16384 + w * 1024; \
    gload16(s_, d_); \
    gload16(s_ + (size_t)64 * 1024, d_ + 8192); \
} while (0)

#define QPHASE(TAU, Q, STGSTMT) do { \
    const int p_ = (TAU) & 1; \
    const __bf16* Ab_ = (const __bf16*)(smem + (p_ * 2 + wm) * 16384); \
    const __bf16* Bb_ = (const __bf16*)(smem + 65536 + (p_ * 2 + bh) * 16384); \
    if ((Q) == 0) { \
        _Pragma("unroll") for (int nf = 0; nf < 4; ++nf) \
        _Pragma("unroll") for (int kk = 0; kk < 2; ++kk) \
            bq[nf][kk] = *(const bf16x8*)(Bb_ + (bro + nf * 16) * 64 + ((kk * 4 + g) ^ rx) * 8); \
    } \
    bf16x8 aq_[2][2]; \
    _Pragma("unroll") for (int i = 0; i < 2; ++i) \
    _Pragma("unroll") for (int kk = 0; kk < 2; ++kk) \
        aq_[i][kk] = *(const bf16x8*)(Ab_ + (((Q) * 2 + i) * 16 + r) * 64 + ((kk * 4 + g) ^ rx) * 8); \
    STGSTMT; \
    BARRIER(); \
    __builtin_amdgcn_s_setprio(1); \
    _Pragma("unroll") for (int i = 0; i < 2; ++i) \
    _Pragma("unroll") for (int nf = 0; nf < 4; ++nf) \
    _Pragma("unroll") for (int kk = 0; kk < 2; ++kk) \
        acc[(Q) * 2 + i][nf] = __builtin_amdgcn_mfma_f32_16x16x32_bf16( \
            aq_[i][kk], bq[nf][kk], acc[(Q) * 2 + i][nf], 0, 0, 0); \
    __builtin_amdgcn_s_setprio(0); \
} while (0)

__global__ __launch_bounds__(512, 2)
void gemm_vg(const __bf16* __restrict__ A, const __bf16* __restrict__ BT,
             __bf16* __restrict__ Vt, __bf16* __restrict__ Gb) {
    __shared__ __align__(16) char smem[131072];

    const int bid = blockIdx.x;
    const int j2 = bid >> 3;                    // 0..31
    const int bxA = (bid & 7) * 2 + (j2 & 1);   // 0..15
    const int by  = j2 >> 1;                    // 0..15
    const int rowBase = by * 256;
    const int colBase = 2048 + bxA * 256;       // packed-WT row offset

    const int tid = threadIdx.x;
    const int w = tid >> 6, lane = tid & 63;
    const int g = lane >> 4, r = lane & 15;
    const int wm = w >> 2, wn = w & 3;
    const int rx = r & 7;
    const int bh = wn >> 1;
    const int bro = (wn & 1) * 64 + r;

    const int srow = lane >> 3;
    const int swz  = ((lane & 7) ^ srow) * 8;

    f32x4 acc[8][4];
    #pragma unroll
    for (int i = 0; i < 8; ++i)
        #pragma unroll
        for (int j = 0; j < 4; ++j)
            acc[i][j] = (f32x4){0.f, 0.f, 0.f, 0.f};
    bf16x8 bq[4][2];

    STAGEH(1, 0, 0); STAGEH(1, 0, 1);
    STAGEH(0, 0, 0); STAGEH(0, 0, 1);
    STAGEH(1, 1, 0); STAGEH(1, 1, 1);
    WAITV(4);
    BARRIER();

    for (int it = 0; it < 8; ++it) {
        const int e = 2 * it, o = e + 1;
        const bool more = (it < 7);
        QPHASE(e, 0, STAGEH(0, o, 0));                        BARRIER();
        QPHASE(e, 1, STAGEH(0, o, 1));                        BARRIER();
        QPHASE(e, 2, if (more) STAGEH(1, e + 2, 0));          BARRIER();
        QPHASE(e, 3, if (more) STAGEH(1, e + 2, 1));
        if (more) { WAITV(4); } else { WAITV(0); }            BARRIER();
        QPHASE(o, 0, if (more) STAGEH(0, e + 2, 0));          BARRIER();
        QPHASE(o, 1, if (more) STAGEH(0, e + 2, 1));          BARRIER();
        QPHASE(o, 2, if (more) STAGEH(1, o + 2, 0));          BARRIER();
        QPHASE(o, 3, if (more) STAGEH(1, o + 2, 1));
        if (more) { WAITV(4); } else { WAITV(0); }            BARRIER();
    }

    if (bxA < 8) {
        // V segment: transposed write to Vt[b][h][d][t]
        __bf16* Es = (__bf16*)smem + w * 4608;
        const int colV0 = (colBase - 2048) + wn * 64;
        const int h = colV0 >> 8, dd0 = colV0 & 255;
        const int li = lane & 7, rgrp = lane >> 3;
        #pragma unroll
        for (int h2 = 0; h2 < 2; ++h2) {
            #pragma unroll
            for (int mf = 0; mf < 4; ++mf)
                #pragma unroll
                for (int nf = 0; nf < 4; ++nf) {
                    f32x4 a = acc[h2 * 4 + mf][nf];
                    bf16x4 v = { (__bf16)a[0], (__bf16)a[1], (__bf16)a[2], (__bf16)a[3] };
                    *reinterpret_cast<bf16x4*>(&Es[(nf * 16 + r) * 72 + mf * 16 + g * 4]) = v;
                }
            __syncthreads();
            const int t0g = rowBase + wm * 128 + h2 * 64;
            const int bq_ = t0g >> 11, tl = t0g & 2047;
            __bf16* vtb = Vt + ((size_t)(bq_ * NHEADS + h) * HDIM + dd0) * T_SEQ + tl;
            #pragma unroll
            for (int c = 0; c < 8; ++c) {
                const int drow = 8 * c + rgrp;
                bf16x8 v = *reinterpret_cast<const bf16x8*>(&Es[drow * 72 + li * 8]);
                *reinterpret_cast<bf16x8*>(vtb + (size_t)drow * T_SEQ + li * 8) = v;
            }
            __syncthreads();
        }
        return;
    }

    const int cofs = colBase - 4096;
    #pragma unroll
    for (int mf = 0; mf < 8; ++mf)
        #pragma unroll
        for (int nf = 0; nf < 4; ++nf)
            #pragma unroll
            for (int j = 0; j < 4; ++j) {
                const int row  = rowBase + wm * 128 + mf * 16 + g * 4 + j;
                const int colL = cofs + wn * 64 + nf * 16 + r;
                Gb[(size_t)row * 2048 + colL] = (__bf16)acc[mf][nf][j];
            }
}

// ============================================================================
// Output projection: 64x128 tile, BK=64, 2-barrier, XCD swizzle.
// ============================================================================
__global__ __launch_bounds__(256)
void gemm_wo(const __bf16* __restrict__ A, const __bf16* __restrict__ BT,
             float* __restrict__ C) {
    constexpr int N = EMBED, K = VDIM;
    __shared__ __align__(16) char smem[24576];
    __bf16* As = (__bf16*)smem;               // [64][64]
    __bf16* Bs = (__bf16*)(smem + 8192);      // [128][64]

    const int bid = blockIdx.x;
    const int swzb = (bid & 7) * 64 + (bid >> 3);
    const int rowBase = (swzb >> 3) * 64;
    const int colBase = (swzb & 7) * 128;

    const int tid = threadIdx.x;
    const int w = tid >> 6, lane = tid & 63;
    const int g = lane >> 4, r = lane & 15;
    const int wm = w >> 1, wn = w & 1;

    const int vr  = lane >> 3;
    const int swz = ((lane & 7) ^ vr) * 8;
    const __bf16* aSb = A  + (size_t)(rowBase + 16 * w + vr) * K + swz;
    const __bf16* bSb = BT + (size_t)(colBase + 32 * w + vr) * K + swz;

    f32x4 acc[2][4];
    #pragma unroll
    for (int i = 0; i < 2; ++i)
        #pragma unroll
        for (int j = 0; j < 4; ++j)
            acc[i][j] = (f32x4){0.f, 0.f, 0.f, 0.f};

    for (int k0 = 0; k0 < K; k0 += 64) {
        __syncthreads();
        #pragma unroll
        for (int p = 0; p < 2; ++p) {
            const int cc = 2 * w + p;
            gload16(aSb + (size_t)(8 * p) * K + k0, smem + cc * 1024);
        }
        #pragma unroll
        for (int p = 0; p < 4; ++p) {
            const int cc = 4 * w + p;
            gload16(bSb + (size_t)(8 * p) * K + k0, smem + 8192 + cc * 1024);
        }
        __syncthreads();

        #pragma unroll
        for (int kk = 0; kk < 2; ++kk) {
            bf16x8 bfrag[4];
            #pragma unroll
            for (int nf = 0; nf < 4; ++nf) {
                const int row = wn * 64 + nf * 16 + r;
                bfrag[nf] = *reinterpret_cast<const bf16x8*>(
                    &Bs[row * 64 + (((kk << 2) + g) ^ (r & 7)) * 8]);
            }
            #pragma unroll
            for (int mf = 0; mf < 2; ++mf) {
                const int row = wm * 32 + mf * 16 + r;
                bf16x8 a = *reinterpret_cast<const bf16x8*>(
                    &As[row * 64 + (((kk << 2) + g) ^ (r & 7)) * 8]);
                #pragma unroll
                for (int nf = 0; nf < 4; ++nf)
                    acc[mf][nf] = __builtin_amdgcn_mfma_f32_16x16x32_bf16(a, bfrag[nf], acc[mf][nf], 0, 0, 0);
            }
        }
    }

    #pragma unroll
    for (int mf = 0; mf < 2; ++mf)
        #pragma unroll
        for (int nf = 0; nf < 4; ++nf)
            #pragma unroll
            for (int j = 0; j < 4; ++j) {
                const int row = rowBase + wm * 32 + mf * 16 + g * 4 + j;
                const int col = colBase + wn * 64 + nf * 16 + r;
                C[(size_t)row * N + col] = acc[mf][nf][j];
            }
}

// ============================================================================
// MFMA retention (R14-best: R11 K-dbuf/V-covered pipeline + R14 mapping),
// + T5 setprio around MFMA clusters (two co-resident blocks per CU run at
// different phases -> scheduler can favor the MFMA-entering wave; m191).
// Ks double-buffered (K(t+1) in flight a full iter), V(t) issue covered by
// QK, counted vmcnt + raw barriers, XCD-pinned h = bid&7.
// ============================================================================
__global__ __launch_bounds__(256)
void retention_mfma(const __bf16* __restrict__ Qb, const __bf16* __restrict__ Kb,
                    const __bf16* __restrict__ Vt,
                    const __bf16* __restrict__ Gb, __bf16* __restrict__ Yb) {
    const int tid = threadIdx.x;
    const int w = tid >> 6, lane = tid & 63;
    const int g = lane >> 4, r = lane & 15;
    const int rx = r & 7;
    const int bid = blockIdx.x;
    const int h = bid & 7;
    const int slot = bid >> 3;
    const int b = slot & 1;
    const int x = slot >> 1;
    const int qt = (b == 0) ? (31 - x) : x;
    const int tt0 = qt * 64;
    const int trow0 = w * 16;

    __shared__ __align__(16) __bf16 Ks[2][64][128];
    __shared__ __align__(16) __bf16 Vs[256][64];
    __shared__ __align__(16) __bf16 Ps[4][16][72];

    const float rho   = 1.0f - exp2f(-(float)(5 + h));
    const float l2r   = log2f(rho);
    const float inv1m = exp2f((float)(5 + h));
    int   tj[4];
    float nrm[4];
    #pragma unroll
    for (int j = 0; j < 4; ++j) {
        tj[j] = tt0 + trow0 + g * 4 + j;
        nrm[j] = rsqrtf((1.0f - exp2f(l2r * (float)(tj[j] + 1))) * inv1m);
    }
    float pneg[4];
    #pragma unroll
    for (int ssub = 0; ssub < 4; ++ssub)
        pneg[ssub] = exp2f(-l2r * (float)(ssub * 16 + r));

    bf16x8 qf[4];
    {
        const __bf16* qrow = Qb + ((size_t)(b * T_SEQ + tt0 + trow0 + r)) * EMBED + h * KDIM;
        #pragma unroll
        for (int kb = 0; kb < 4; ++kb)
            qf[kb] = *reinterpret_cast<const bf16x8*>(qrow + kb * 32 + g * 8);
    }

    f32x4 acc[16];
    #pragma unroll
    for (int db = 0; db < 16; ++db) acc[db] = (f32x4){0.f, 0.f, 0.f, 0.f};
    float dsum[4] = {0.f, 0.f, 0.f, 0.f};

    const __bf16* vtbase = Vt + ((size_t)(b * NHEADS + h) * HDIM) * T_SEQ;
    const __bf16* kbase  = Kb + ((size_t)(b * T_SEQ)) * EMBED + h * KDIM;

    const int klr = lane >> 4;
    const int kc  = lane & 15;
    const int kswz_even = (kc ^ klr) * 8;
    const int kswz_odd  = (kc ^ (4 + klr)) * 8;
    const int vlr  = lane >> 3;
    const int vswz = ((lane & 7) ^ vlr) * 8;

    #pragma unroll
    for (int p = 0; p < 4; ++p) {
        const int cc = 4 * w + p;
        const int se = (p & 1) ? kswz_odd : kswz_even;
        gload16(kbase + (size_t)(4 * cc + klr) * EMBED + se,
                (char*)&Ks[0][0][0] + cc * 1024);
    }

    int cur = 0;
    const int nS = qt + 1;
    for (int st = 0; st < nS; ++st) {
        const int ss0 = st * 64;
        WAITV(0);
        BARRIER();

        #pragma unroll
        for (int p = 0; p < 8; ++p) {
            const int cc = 8 * w + p;
            gload16(vtbase + (size_t)(8 * cc + vlr) * T_SEQ + ss0 + vswz,
                    (char*)&Vs[0][0] + cc * 1024);
        }
        const bool more = (st + 1 < nS);
        if (more) {
            const int ssn = ss0 + 64;
            #pragma unroll
            for (int p = 0; p < 4; ++p) {
                const int cc = 4 * w + p;
                const int se = (p & 1) ? kswz_odd : kswz_even;
                gload16(kbase + (size_t)(ssn + 4 * cc + klr) * EMBED + se,
                        (char*)&Ks[cur ^ 1][0][0] + cc * 1024);
            }
        }

        float wj[4];
        #pragma unroll
        for (int j = 0; j < 4; ++j)
            wj[j] = exp2f(l2r * (float)(tj[j] - ss0)) * nrm[j];
        const bool diag = (st == qt);

        __builtin_amdgcn_s_setprio(1);
        #pragma unroll
        for (int ssub = 0; ssub < 4; ++ssub) {
            f32x4 sacc = (f32x4){0.f, 0.f, 0.f, 0.f};
            #pragma unroll
            for (int kb = 0; kb < 4; ++kb) {
                bf16x8 kf = *reinterpret_cast<const bf16x8*>(
                    &Ks[cur][ssub * 16 + r][((kb * 4 + g) ^ rx) * 8]);
                sacc = __builtin_amdgcn_mfma_f32_16x16x32_bf16(qf[kb], kf, sacc, 0, 0, 0);
            }
            const int scol = ss0 + ssub * 16 + r;
            const float mfac = pneg[ssub];
            #pragma unroll
            for (int j = 0; j < 4; ++j) {
                float pv = sacc[j] * (wj[j] * mfac);
                if (diag && scol > tj[j]) pv = 0.f;
                dsum[j] += fabsf(pv);
                Ps[w][g * 4 + j][ssub * 16 + r] = (__bf16)pv;
            }
        }
        __builtin_amdgcn_s_setprio(0);

        if (more) { WAITV(4); } else { WAITV(0); }
        BARRIER();

        __builtin_amdgcn_s_setprio(1);
        #pragma unroll
        for (int sh = 0; sh < 2; ++sh) {
            bf16x8 pf = *reinterpret_cast<const bf16x8*>(&Ps[w][r][sh * 32 + g * 8]);
            #pragma unroll
            for (int db = 0; db < 16; ++db) {
                bf16x8 vf = *reinterpret_cast<const bf16x8*>(
                    &Vs[db * 16 + r][((sh * 4 + g) ^ rx) * 8]);
                acc[db] = __builtin_amdgcn_mfma_f32_16x16x32_bf16(pf, vf, acc[db], 0, 0, 0);
            }
        }
        __builtin_amdgcn_s_setprio(0);
        cur ^= 1;
    }

    #pragma unroll
    for (int j = 0; j < 4; ++j) {
        float v = dsum[j];
        v += __shfl_xor(v, 1); v += __shfl_xor(v, 2);
        v += __shfl_xor(v, 4); v += __shfl_xor(v, 8);
        dsum[j] = fminf(fmaxf(v, 1.0f), 50000.0f);
    }
    float ss[4] = {0.f, 0.f, 0.f, 0.f};
    #pragma unroll
    for (int db = 0; db < 16; ++db)
        #pragma unroll
        for (int j = 0; j < 4; ++j) {
            const float v = acc[db][j] / dsum[j];
            acc[db][j] = v;
            ss[j] = fmaf(v, v, ss[j]);
        }
    #pragma unroll
    for (int j = 0; j < 4; ++j) {
        float v = ss[j];
        v += __shfl_xor(v, 1); v += __shfl_xor(v, 2);
        v += __shfl_xor(v, 4); v += __shfl_xor(v, 8);
        ss[j] = rsqrtf(v * (1.0f / 256.0f) + EPS);
    }
    #pragma unroll
    for (int j = 0; j < 4; ++j) {
        const size_t row = (size_t)(b * T_SEQ + tj[j]);
        const __bf16* grow = Gb + row * VDIM + h * HDIM;
        __bf16* yrow = Yb + row * VDIM + h * HDIM;
        #pragma unroll
        for (int db = 0; db < 16; ++db) {
            const int c = db * 16 + r;
            const float gv = (float)grow[c];
            const float sil = gv / (1.0f + expf(-gv));
            yrow[c] = (__bf16)(sil * acc[db][j] * ss[j]);
        }
    }
}

// ============================================================================
// launch
// ============================================================================
extern "C" void kernel_launch(void* const* d_in, const int* in_sizes, int n_in,
                              void* d_out, int out_size, void* d_ws, size_t ws_size,
                              hipStream_t stream) {
    (void)in_sizes; (void)n_in; (void)out_size; (void)ws_size;

    const float* x    = (const float*)d_in[0];
    const float* sinT = (const float*)d_in[1];
    const float* cosT = (const float*)d_in[2];
    // d_in[3] (mask) is recomputed on the fly in retention_mfma
    const float* Wq   = (const float*)d_in[4];
    const float* Wk   = (const float*)d_in[5];
    const float* Wv   = (const float*)d_in[6];
    const float* Wg   = (const float*)d_in[7];
    const float* Wo   = (const float*)d_in[8];
    float* out = (float*)d_out;

    // workspace layout (bytes). WqT..WgT contiguous -> packed [6144][1024].
    char* wsp = (char*)d_ws;
    __bf16* xb  = (__bf16*)(wsp);
    __bf16* WqT = (__bf16*)(wsp + (8u  << 20));
    __bf16* WkT = (__bf16*)(wsp + (10u << 20));
    __bf16* WvT = (__bf16*)(wsp + (12u << 20));
    __bf16* WgT = (__bf16*)(wsp + (16u << 20));
    __bf16* WoT = (__bf16*)(wsp + (20u << 20));
    __bf16* Qb  = (__bf16*)(wsp + (24u << 20));
    __bf16* Kb  = (__bf16*)(wsp + (32u << 20));
    __bf16* Yb  = (__bf16*)(wsp + (40u << 20));  // retention output (gated)
    __bf16* Gb  = (__bf16*)(wsp + (56u << 20));
    __bf16* Vt  = (__bf16*)(wsp + (72u << 20));
    __bf16* WTall = WqT;                         // packed Q|K|V|G weights

    const dim3 blk(256);
    const dim3 tblk(32, 8);

    // ---- prep (merged transposes + x convert) ----
    prep_all<<<12288, tblk, 0, stream>>>(x, Wq, Wk, Wv, Wg, Wo,
                                         xb, WqT, WkT, WvT, WgT, WoT);

    // ---- Q|K projection (proven 2-barrier 128^2; RoPE + kscale) ----
    gemm_qk<<<512, blk, 0, stream>>>(xb, WTall, Qb, Kb, sinT, cosT);

    // ---- V|G projection (8-phase 256^2, grid = exactly 1/CU) ----
    gemm_vg<<<256, 512, 0, stream>>>(xb, WTall, Vt, Gb);

    // ---- fused retention (R14-best pipeline + setprio) ----
    retention_mfma<<<512, blk, 0, stream>>>(Qb, Kb, Vt, Gb, Yb);

    // ---- output projection ----
    gemm_wo<<<512, blk, 0, stream>>>(Yb, WoT, out);
}

// Round 19
// 171.153 us; speedup vs baseline: 2.1645x; 1.0058x over previous
//
#include <hip/hip_runtime.h>
#include <hip/hip_bf16.h>
#include <math.h>

// ---- problem constants (MultiScaleRetention, B=2,T=2048,E=1024,V=2048,H=8) ----
constexpr int T_SEQ = 2048;
constexpr int BB    = 2;
constexpr int EMBED = 1024;
constexpr int VDIM  = 2048;
constexpr int NHEADS = 8;
constexpr int KDIM  = 128;
constexpr int HDIM  = 256;
constexpr int ROWS  = BB * T_SEQ;  // 4096
constexpr float EPS = 1e-6f;

typedef float  f32x4  __attribute__((ext_vector_type(4)));
typedef __bf16 bf16x8 __attribute__((ext_vector_type(8)));
typedef __bf16 bf16x4 __attribute__((ext_vector_type(4)));

// async global->LDS, 16B per lane. LDS dest is wave-uniform base + lane*16;
// global src is per-lane.
__device__ __forceinline__ void gload16(const void* g, void* l) {
    __builtin_amdgcn_global_load_lds(
        (__attribute__((address_space(1))) void*)g,
        (__attribute__((address_space(3))) void*)l, 16, 0, 0);
}

#define WAITV(n) asm volatile("s_waitcnt vmcnt(" #n ")" ::: "memory")
#define WAITLGKM() asm volatile("s_waitcnt lgkmcnt(0)" ::: "memory")
#define BARRIER() __builtin_amdgcn_s_barrier()

// ============================================================================
// Merged prep: five W[K][N] f32 -> WT[N][K] bf16 transposes (bid < 8192)
// + x f32->bf16 convert (bid >= 8192). One launch.
// ============================================================================
__global__ __launch_bounds__(256)
void prep_all(const float* __restrict__ x, const float* __restrict__ Wq,
              const float* __restrict__ Wk, const float* __restrict__ Wv,
              const float* __restrict__ Wg, const float* __restrict__ Wo,
              __bf16* __restrict__ xb,
              __bf16* __restrict__ WqT, __bf16* __restrict__ WkT,
              __bf16* __restrict__ WvT, __bf16* __restrict__ WgT,
              __bf16* __restrict__ WoT) {
    const int bid = blockIdx.x;
    const int x_ = threadIdx.x, y_ = threadIdx.y;
    if (bid >= 8192) {
        const int i = (bid - 8192) * 256 + y_ * 32 + x_;
        float4 v = reinterpret_cast<const float4*>(x)[i];
        bf16x4 o = { (__bf16)v.x, (__bf16)v.y, (__bf16)v.z, (__bf16)v.w };
        reinterpret_cast<bf16x4*>(xb)[i] = o;
        return;
    }
    const float* W; __bf16* WT; int K, N, cx, cy;
    if (bid < 1024)      { W = Wq; WT = WqT; K = 1024; N = 1024; int rm = bid;        cx = rm & 31; cy = rm >> 5; }
    else if (bid < 2048) { W = Wk; WT = WkT; K = 1024; N = 1024; int rm = bid - 1024; cx = rm & 31; cy = rm >> 5; }
    else if (bid < 4096) { W = Wv; WT = WvT; K = 1024; N = 2048; int rm = bid - 2048; cx = rm & 63; cy = rm >> 6; }
    else if (bid < 6144) { W = Wg; WT = WgT; K = 1024; N = 2048; int rm = bid - 4096; cx = rm & 63; cy = rm >> 6; }
    else                 { W = Wo; WT = WoT; K = 2048; N = 1024; int rm = bid - 6144; cx = rm & 31; cy = rm >> 5; }

    __shared__ float tile[32][33];
    const int c0 = cx * 32, k0 = cy * 32;
    #pragma unroll
    for (int p = 0; p < 4; ++p)
        tile[y_ + p * 8][x_] = W[(size_t)(k0 + y_ + p * 8) * N + c0 + x_];
    __syncthreads();
    #pragma unroll
    for (int p = 0; p < 4; ++p)
        WT[(size_t)(c0 + y_ + p * 8) * K + k0 + x_] = (__bf16)tile[x_][y_ + p * 8];
}

// ============================================================================
// Kernel B: Q|K projection GEMM (2-barrier m97, 128x128, BK=64, G4 swizzle).
// RoPE + kscale in epilogue. Grid 512 = 2/CU; XCD col-pinning.
// ============================================================================
__global__ __launch_bounds__(256)
void gemm_qk(const __bf16* __restrict__ A, const __bf16* __restrict__ BT,
             __bf16* __restrict__ Qb, __bf16* __restrict__ Kb,
             const float* __restrict__ sinT, const float* __restrict__ cosT) {
    constexpr int K = EMBED;
    __shared__ __align__(16) char smem[32768];
    __bf16* As = (__bf16*)smem;               // [128][64] linear, swizzled
    __bf16* Bs = (__bf16*)(smem + 16384);     // [128][64] linear, swizzled

    const int bid = blockIdx.x;
    const int rr = bid >> 3;                  // 0..63
    const int bx = (bid & 7) * 2 + (rr & 1);  // 0..15 (2 cols per XCD)
    const int by = rr >> 1;                   // 0..31
    const int rowBase = by * 128;
    const int colBase = bx * 128;

    const int tid = threadIdx.x;
    const int w = tid >> 6, lane = tid & 63;
    const int g = lane >> 4, r = lane & 15;
    const int wm = w >> 1, wn = w & 1;

    const int vr  = lane >> 3;
    const int swz = ((lane & 7) ^ vr) * 8;
    const __bf16* aSb = A  + (size_t)(rowBase + 32 * w + vr) * K + swz;
    const __bf16* bSb = BT + (size_t)(colBase + 32 * w + vr) * K + swz;

    f32x4 acc[4][4];
    #pragma unroll
    for (int i = 0; i < 4; ++i)
        #pragma unroll
        for (int j = 0; j < 4; ++j)
            acc[i][j] = (f32x4){0.f, 0.f, 0.f, 0.f};

    for (int k0 = 0; k0 < K; k0 += 64) {
        __syncthreads();
        #pragma unroll
        for (int p = 0; p < 4; ++p) {
            const int cc = 4 * w + p;
            gload16(aSb + (size_t)(8 * p) * K + k0, smem         + cc * 1024);
            gload16(bSb + (size_t)(8 * p) * K + k0, smem + 16384 + cc * 1024);
        }
        __syncthreads();

        #pragma unroll
        for (int kk = 0; kk < 2; ++kk) {
            bf16x8 bfrag[4];
            #pragma unroll
            for (int nf = 0; nf < 4; ++nf) {
                const int row = wn * 64 + nf * 16 + r;
                bfrag[nf] = *reinterpret_cast<const bf16x8*>(
                    &Bs[row * 64 + (((kk << 2) + g) ^ (r & 7)) * 8]);
            }
            #pragma unroll
            for (int mf = 0; mf < 4; ++mf) {
                const int row = wm * 64 + mf * 16 + r;
                bf16x8 a = *reinterpret_cast<const bf16x8*>(
                    &As[row * 64 + (((kk << 2) + g) ^ (r & 7)) * 8]);
                #pragma unroll
                for (int nf = 0; nf < 4; ++nf)
                    acc[mf][nf] = __builtin_amdgcn_mfma_f32_16x16x32_bf16(a, bfrag[nf], acc[mf][nf], 0, 0, 0);
            }
        }
    }

    constexpr float kscale = 0.08838834764831845f;  // KEY_DIM^-0.5
    __bf16* dst; int cofs; float alphaSeg;
    if (colBase < 1024) { dst = Qb; cofs = colBase;        alphaSeg = 1.0f;   }
    else                { dst = Kb; cofs = colBase - 1024; alphaSeg = kscale; }

    #pragma unroll
    for (int mf = 0; mf < 4; ++mf)
        #pragma unroll
        for (int nf = 0; nf < 4; ++nf)
            #pragma unroll
            for (int j = 0; j < 4; ++j) {
                const int row  = rowBase + wm * 64 + mf * 16 + g * 4 + j;
                const int colL = cofs + wn * 64 + nf * 16 + r;
                float v = acc[mf][nf][j] * alphaSeg;
                const float p = __shfl_xor(v, 1);
                const int t  = row & (T_SEQ - 1);
                const int dh = colL & (KDIM - 1);
                const float c = cosT[t * KDIM + dh];
                const float s = sinT[t * KDIM + dh];
                v = (r & 1) ? (v * c + p * s) : (v * c - p * s);
                dst[(size_t)row * 1024 + colL] = (__bf16)v;
            }
}

// ============================================================================
// Kernel A: V|G projection GEMM — 256x256 8-PHASE, grid 256 = 1/CU.
// ============================================================================
#define STAGEH(ISB, TAU, HF) do { \
    const __bf16* s_ = ((ISB) ? BT : A) + \
        (size_t)((((ISB) ? colBase : rowBase)) + (HF) * 128 + w * 8 + srow) * 1024 + \
        (TAU) * 64 + swz; \
    char* d_ = smem + ((ISB) ? 65536 : 0) + (((TAU) & 1) * 2 + (HF)) * 16384 + w * 1024; \
    gload16(s_, d_); \
    gload16(s_ + (size_t)64 * 1024, d_ + 8192); \
} while (0)

#define QPHASE(TAU, Q, STGSTMT) do { \
    const int p_ = (TAU) & 1; \
    const __bf16* Ab_ = (const __bf16*)(smem + (p_ * 2 + wm) * 16384); \
    const __bf16* Bb_ = (const __bf16*)(smem + 65536 + (p_ * 2 + bh) * 16384); \
    if ((Q) == 0) { \
        _Pragma("unroll") for (int nf = 0; nf < 4; ++nf) \
        _Pragma("unroll") for (int kk = 0; kk < 2; ++kk) \
            bq[nf][kk] = *(const bf16x8*)(Bb_ + (bro + nf * 16) * 64 + ((kk * 4 + g) ^ rx) * 8); \
    } \
    bf16x8 aq_[2][2]; \
    _Pragma("unroll") for (int i = 0; i < 2; ++i) \
    _Pragma("unroll") for (int kk = 0; kk < 2; ++kk) \
        aq_[i][kk] = *(const bf16x8*)(Ab_ + (((Q) * 2 + i) * 16 + r) * 64 + ((kk * 4 + g) ^ rx) * 8); \
    STGSTMT; \
    BARRIER(); \
    __builtin_amdgcn_s_setprio(1); \
    _Pragma("unroll") for (int i = 0; i < 2; ++i) \
    _Pragma("unroll") for (int nf = 0; nf < 4; ++nf) \
    _Pragma("unroll") for (int kk = 0; kk < 2; ++kk) \
        acc[(Q) * 2 + i][nf] = __builtin_amdgcn_mfma_f32_16x16x32_bf16( \
            aq_[i][kk], bq[nf][kk], acc[(Q) * 2 + i][nf], 0, 0, 0); \
    __builtin_amdgcn_s_setprio(0); \
} while (0)

__global__ __launch_bounds__(512, 2)
void gemm_vg(const __bf16* __restrict__ A, const __bf16* __restrict__ BT,
             __bf16* __restrict__ Vt, __bf16* __restrict__ Gb) {
    __shared__ __align__(16) char smem[131072];

    const int bid = blockIdx.x;
    const int j2 = bid >> 3;                    // 0..31
    const int bxA = (bid & 7) * 2 + (j2 & 1);   // 0..15
    const int by  = j2 >> 1;                    // 0..15
    const int rowBase = by * 256;
    const int colBase = 2048 + bxA * 256;       // packed-WT row offset

    const int tid = threadIdx.x;
    const int w = tid >> 6, lane = tid & 63;
    const int g = lane >> 4, r = lane & 15;
    const int wm = w >> 2, wn = w & 3;
    const int rx = r & 7;
    const int bh = wn >> 1;
    const int bro = (wn & 1) * 64 + r;

    const int srow = lane >> 3;
    const int swz  = ((lane & 7) ^ srow) * 8;

    f32x4 acc[8][4];
    #pragma unroll
    for (int i = 0; i < 8; ++i)
        #pragma unroll
        for (int j = 0; j < 4; ++j)
            acc[i][j] = (f32x4){0.f, 0.f, 0.f, 0.f};
    bf16x8 bq[4][2];

    STAGEH(1, 0, 0); STAGEH(1, 0, 1);
    STAGEH(0, 0, 0); STAGEH(0, 0, 1);
    STAGEH(1, 1, 0); STAGEH(1, 1, 1);
    WAITV(4);
    BARRIER();

    for (int it = 0; it < 8; ++it) {
        const int e = 2 * it, o = e + 1;
        const bool more = (it < 7);
        QPHASE(e, 0, STAGEH(0, o, 0));                        BARRIER();
        QPHASE(e, 1, STAGEH(0, o, 1));                        BARRIER();
        QPHASE(e, 2, if (more) STAGEH(1, e + 2, 0));          BARRIER();
        QPHASE(e, 3, if (more) STAGEH(1, e + 2, 1));
        if (more) { WAITV(4); } else { WAITV(0); }            BARRIER();
        QPHASE(o, 0, if (more) STAGEH(0, e + 2, 0));          BARRIER();
        QPHASE(o, 1, if (more) STAGEH(0, e + 2, 1));          BARRIER();
        QPHASE(o, 2, if (more) STAGEH(1, o + 2, 0));          BARRIER();
        QPHASE(o, 3, if (more) STAGEH(1, o + 2, 1));
        if (more) { WAITV(4); } else { WAITV(0); }            BARRIER();
    }

    if (bxA < 8) {
        // V segment: transposed write to Vt[b][h][d][t]
        __bf16* Es = (__bf16*)smem + w * 4608;
        const int colV0 = (colBase - 2048) + wn * 64;
        const int h = colV0 >> 8, dd0 = colV0 & 255;
        const int li = lane & 7, rgrp = lane >> 3;
        #pragma unroll
        for (int h2 = 0; h2 < 2; ++h2) {
            #pragma unroll
            for (int mf = 0; mf < 4; ++mf)
                #pragma unroll
                for (int nf = 0; nf < 4; ++nf) {
                    f32x4 a = acc[h2 * 4 + mf][nf];
                    bf16x4 v = { (__bf16)a[0], (__bf16)a[1], (__bf16)a[2], (__bf16)a[3] };
                    *reinterpret_cast<bf16x4*>(&Es[(nf * 16 + r) * 72 + mf * 16 + g * 4]) = v;
                }
            __syncthreads();
            const int t0g = rowBase + wm * 128 + h2 * 64;
            const int bq_ = t0g >> 11, tl = t0g & 2047;
            __bf16* vtb = Vt + ((size_t)(bq_ * NHEADS + h) * HDIM + dd0) * T_SEQ + tl;
            #pragma unroll
            for (int c = 0; c < 8; ++c) {
                const int drow = 8 * c + rgrp;
                bf16x8 v = *reinterpret_cast<const bf16x8*>(&Es[drow * 72 + li * 8]);
                *reinterpret_cast<bf16x8*>(vtb + (size_t)drow * T_SEQ + li * 8) = v;
            }
            __syncthreads();
        }
        return;
    }

    const int cofs = colBase - 4096;
    #pragma unroll
    for (int mf = 0; mf < 8; ++mf)
        #pragma unroll
        for (int nf = 0; nf < 4; ++nf)
            #pragma unroll
            for (int j = 0; j < 4; ++j) {
                const int row  = rowBase + wm * 128 + mf * 16 + g * 4 + j;
                const int colL = cofs + wn * 64 + nf * 16 + r;
                Gb[(size_t)row * 2048 + colL] = (__bf16)acc[mf][nf][j];
            }
}

// ============================================================================
// Output projection: 64x128 tile, BK=64, 2-barrier, XCD swizzle.
// ============================================================================
__global__ __launch_bounds__(256)
void gemm_wo(const __bf16* __restrict__ A, const __bf16* __restrict__ BT,
             float* __restrict__ C) {
    constexpr int N = EMBED, K = VDIM;
    __shared__ __align__(16) char smem[24576];
    __bf16* As = (__bf16*)smem;               // [64][64]
    __bf16* Bs = (__bf16*)(smem + 8192);      // [128][64]

    const int bid = blockIdx.x;
    const int swzb = (bid & 7) * 64 + (bid >> 3);
    const int rowBase = (swzb >> 3) * 64;
    const int colBase = (swzb & 7) * 128;

    const int tid = threadIdx.x;
    const int w = tid >> 6, lane = tid & 63;
    const int g = lane >> 4, r = lane & 15;
    const int wm = w >> 1, wn = w & 1;

    const int vr  = lane >> 3;
    const int swz = ((lane & 7) ^ vr) * 8;
    const __bf16* aSb = A  + (size_t)(rowBase + 16 * w + vr) * K + swz;
    const __bf16* bSb = BT + (size_t)(colBase + 32 * w + vr) * K + swz;

    f32x4 acc[2][4];
    #pragma unroll
    for (int i = 0; i < 2; ++i)
        #pragma unroll
        for (int j = 0; j < 4; ++j)
            acc[i][j] = (f32x4){0.f, 0.f, 0.f, 0.f};

    for (int k0 = 0; k0 < K; k0 += 64) {
        __syncthreads();
        #pragma unroll
        for (int p = 0; p < 2; ++p) {
            const int cc = 2 * w + p;
            gload16(aSb + (size_t)(8 * p) * K + k0, smem + cc * 1024);
        }
        #pragma unroll
        for (int p = 0; p < 4; ++p) {
            const int cc = 4 * w + p;
            gload16(bSb + (size_t)(8 * p) * K + k0, smem + 8192 + cc * 1024);
        }
        __syncthreads();

        #pragma unroll
        for (int kk = 0; kk < 2; ++kk) {
            bf16x8 bfrag[4];
            #pragma unroll
            for (int nf = 0; nf < 4; ++nf) {
                const int row = wn * 64 + nf * 16 + r;
                bfrag[nf] = *reinterpret_cast<const bf16x8*>(
                    &Bs[row * 64 + (((kk << 2) + g) ^ (r & 7)) * 8]);
            }
            #pragma unroll
            for (int mf = 0; mf < 2; ++mf) {
                const int row = wm * 32 + mf * 16 + r;
                bf16x8 a = *reinterpret_cast<const bf16x8*>(
                    &As[row * 64 + (((kk << 2) + g) ^ (r & 7)) * 8]);
                #pragma unroll
                for (int nf = 0; nf < 4; ++nf)
                    acc[mf][nf] = __builtin_amdgcn_mfma_f32_16x16x32_bf16(a, bfrag[nf], acc[mf][nf], 0, 0, 0);
            }
        }
    }

    #pragma unroll
    for (int mf = 0; mf < 2; ++mf)
        #pragma unroll
        for (int nf = 0; nf < 4; ++nf)
            #pragma unroll
            for (int j = 0; j < 4; ++j) {
                const int row = rowBase + wm * 32 + mf * 16 + g * 4 + j;
                const int col = colBase + wn * 64 + nf * 16 + r;
                C[(size_t)row * N + col] = acc[mf][nf][j];
            }
}

// ============================================================================
// MFMA retention — R11/R14 pipelined skeleton + 4x4 outer-product PV.
// LDS-BW model: old PV read ALL of Vs per wave (32 b128) -> 5600cy/CU/step
// = measured 5760. New: Ps SHARED [64][72]; wave w owns d-cols [64w,64w+64)
// x all 64 q -> 8 pf + 8 vf reads. Block LDS time/tile ~2800->~1900cy.
// 2 barriers/tile kept (R9's 3-barrier version collapsed); lgkmcnt(0) added
// before mid raw-barrier (cross-wave Ps visibility; raw s_barrier does not
// drain LDS). Epilogue: R9-verified dsumL/ssL cross-wave reduction.
// ============================================================================
__global__ __launch_bounds__(256)
void retention_mfma(const __bf16* __restrict__ Qb, const __bf16* __restrict__ Kb,
                    const __bf16* __restrict__ Vt,
                    const __bf16* __restrict__ Gb, __bf16* __restrict__ Yb) {
    const int tid = threadIdx.x;
    const int w = tid >> 6, lane = tid & 63;
    const int g = lane >> 4, r = lane & 15;
    const int rx = r & 7;
    const int bid = blockIdx.x;
    const int h = bid & 7;
    const int slot = bid >> 3;
    const int b = slot & 1;
    const int x = slot >> 1;
    const int qt = (b == 0) ? (31 - x) : x;
    const int tt0 = qt * 64;
    const int trow0 = w * 16;

    __shared__ __align__(16) __bf16 Ks[2][64][128];
    __shared__ __align__(16) __bf16 Vs[256][64];
    __shared__ __align__(16) __bf16 Ps[64][72];   // SHARED P tile, +8 pad
    __shared__ float dsumL[64];
    __shared__ float ssL[4][64];

    const float rho   = 1.0f - exp2f(-(float)(5 + h));
    const float l2r   = log2f(rho);
    const float inv1m = exp2f((float)(5 + h));
    int   tj[4];
    float nrm[4];
    #pragma unroll
    for (int j = 0; j < 4; ++j) {
        tj[j] = tt0 + trow0 + g * 4 + j;
        nrm[j] = rsqrtf((1.0f - exp2f(l2r * (float)(tj[j] + 1))) * inv1m);
    }
    float pneg[4];
    #pragma unroll
    for (int ssub = 0; ssub < 4; ++ssub)
        pneg[ssub] = exp2f(-l2r * (float)(ssub * 16 + r));

    bf16x8 qf[4];
    {
        const __bf16* qrow = Qb + ((size_t)(b * T_SEQ + tt0 + trow0 + r)) * EMBED + h * KDIM;
        #pragma unroll
        for (int kb = 0; kb < 4; ++kb)
            qf[kb] = *reinterpret_cast<const bf16x8*>(qrow + kb * 32 + g * 8);
    }

    // PV accumulator: [qsub][dsub] -> q = qsub*16+g*4+j, d = w*64+dsub*16+r
    f32x4 acc[4][4];
    #pragma unroll
    for (int qs = 0; qs < 4; ++qs)
        #pragma unroll
        for (int ds = 0; ds < 4; ++ds)
            acc[qs][ds] = (f32x4){0.f, 0.f, 0.f, 0.f};
    float dsum[4] = {0.f, 0.f, 0.f, 0.f};

    const __bf16* vtbase = Vt + ((size_t)(b * NHEADS + h) * HDIM) * T_SEQ;
    const __bf16* kbase  = Kb + ((size_t)(b * T_SEQ)) * EMBED + h * KDIM;

    const int klr = lane >> 4;
    const int kc  = lane & 15;
    const int kswz_even = (kc ^ klr) * 8;
    const int kswz_odd  = (kc ^ (4 + klr)) * 8;
    const int vlr  = lane >> 3;
    const int vswz = ((lane & 7) ^ vlr) * 8;

    #pragma unroll
    for (int p = 0; p < 4; ++p) {
        const int cc = 4 * w + p;
        const int se = (p & 1) ? kswz_odd : kswz_even;
        gload16(kbase + (size_t)(4 * cc + klr) * EMBED + se,
                (char*)&Ks[0][0][0] + cc * 1024);
    }

    int cur = 0;
    const int nS = qt + 1;
    for (int st = 0; st < nS; ++st) {
        const int ss0 = st * 64;
        WAITV(0);
        BARRIER();   // K(st) visible; prev PV's Ps/Vs reads all consumed

        #pragma unroll
        for (int p = 0; p < 8; ++p) {
            const int cc = 8 * w + p;
            gload16(vtbase + (size_t)(8 * cc + vlr) * T_SEQ + ss0 + vswz,
                    (char*)&Vs[0][0] + cc * 1024);
        }
        const bool more = (st + 1 < nS);
        if (more) {
            const int ssn = ss0 + 64;
            #pragma unroll
            for (int p = 0; p < 4; ++p) {
                const int cc = 4 * w + p;
                const int se = (p & 1) ? kswz_odd : kswz_even;
                gload16(kbase + (size_t)(ssn + 4 * cc + klr) * EMBED + se,
                        (char*)&Ks[cur ^ 1][0][0] + cc * 1024);
            }
        }

        float wj[4];
        #pragma unroll
        for (int j = 0; j < 4; ++j)
            wj[j] = exp2f(l2r * (float)(tj[j] - ss0)) * nrm[j];
        const bool diag = (st == qt);

        // ---- QK^T (own 16 q-rows x all 64 s) -> SHARED Ps ----
        __builtin_amdgcn_s_setprio(1);
        #pragma unroll
        for (int ssub = 0; ssub < 4; ++ssub) {
            f32x4 sacc = (f32x4){0.f, 0.f, 0.f, 0.f};
            #pragma unroll
            for (int kb = 0; kb < 4; ++kb) {
                bf16x8 kf = *reinterpret_cast<const bf16x8*>(
                    &Ks[cur][ssub * 16 + r][((kb * 4 + g) ^ rx) * 8]);
                sacc = __builtin_amdgcn_mfma_f32_16x16x32_bf16(qf[kb], kf, sacc, 0, 0, 0);
            }
            const int scol = ss0 + ssub * 16 + r;
            const float mfac = pneg[ssub];
            #pragma unroll
            for (int j = 0; j < 4; ++j) {
                float pv = sacc[j] * (wj[j] * mfac);
                if (diag && scol > tj[j]) pv = 0.f;
                dsum[j] += fabsf(pv);
                Ps[trow0 + g * 4 + j][ssub * 16 + r] = (__bf16)pv;
            }
        }
        __builtin_amdgcn_s_setprio(0);

        if (more) { WAITV(4); } else { WAITV(0); }
        WAITLGKM();   // drain Ps ds_writes (cross-wave visibility)
        BARRIER();    // all waves: Ps(st) + Vs(st) visible

        // ---- PV 4x4: wave w owns d-cols [64w,64w+64) x all 64 q ----
        __builtin_amdgcn_s_setprio(1);
        #pragma unroll
        for (int sh = 0; sh < 2; ++sh) {
            bf16x8 pf[4];
            #pragma unroll
            for (int qs = 0; qs < 4; ++qs)
                pf[qs] = *reinterpret_cast<const bf16x8*>(
                    &Ps[qs * 16 + r][sh * 32 + g * 8]);
            #pragma unroll
            for (int ds = 0; ds < 4; ++ds) {
                bf16x8 vf = *reinterpret_cast<const bf16x8*>(
                    &Vs[w * 64 + ds * 16 + r][((sh * 4 + g) ^ rx) * 8]);
                #pragma unroll
                for (int qs = 0; qs < 4; ++qs)
                    acc[qs][ds] = __builtin_amdgcn_mfma_f32_16x16x32_bf16(pf[qs], vf, acc[qs][ds], 0, 0, 0);
            }
        }
        __builtin_amdgcn_s_setprio(0);
        cur ^= 1;
    }

    // ---- epilogue (R9-verified cross-wave reduction) ----
    // 1) finalize per-row dsum (this wave's 16 rows), clip, publish
    #pragma unroll
    for (int j = 0; j < 4; ++j) {
        float v = dsum[j];
        v += __shfl_xor(v, 1); v += __shfl_xor(v, 2);
        v += __shfl_xor(v, 4); v += __shfl_xor(v, 8);
        dsum[j] = fminf(fmaxf(v, 1.0f), 50000.0f);
    }
    if (r == 0) {
        #pragma unroll
        for (int j = 0; j < 4; ++j)
            dsumL[trow0 + g * 4 + j] = dsum[j];
    }
    __syncthreads();

    // 2) divide by denom; RMS partials over this wave's 64 d-cols
    #pragma unroll
    for (int qs = 0; qs < 4; ++qs)
        #pragma unroll
        for (int j = 0; j < 4; ++j) {
            const float inv = 1.0f / dsumL[qs * 16 + g * 4 + j];
            float sp = 0.f;
            #pragma unroll
            for (int ds = 0; ds < 4; ++ds) {
                const float v = acc[qs][ds][j] * inv;
                acc[qs][ds][j] = v;
                sp = fmaf(v, v, sp);
            }
            sp += __shfl_xor(sp, 1); sp += __shfl_xor(sp, 2);
            sp += __shfl_xor(sp, 4); sp += __shfl_xor(sp, 8);
            if (r == 0) ssL[w][qs * 16 + g * 4 + j] = sp;
        }
    __syncthreads();

    // 3) total RMS, silu(g) gate, write Y (wave w writes cols [64w, 64w+64))
    #pragma unroll
    for (int qs = 0; qs < 4; ++qs)
        #pragma unroll
        for (int j = 0; j < 4; ++j) {
            const int ql = qs * 16 + g * 4 + j;
            const float tot = ssL[0][ql] + ssL[1][ql] + ssL[2][ql] + ssL[3][ql];
            const float rs = rsqrtf(tot * (1.0f / 256.0f) + EPS);
            const size_t row = (size_t)(b * T_SEQ + tt0 + ql);
            const __bf16* grow = Gb + row * VDIM + h * HDIM;
            __bf16* yrow = Yb + row * VDIM + h * HDIM;
            #pragma unroll
            for (int ds = 0; ds < 4; ++ds) {
                const int c = w * 64 + ds * 16 + r;
                const float gv = (float)grow[c];
                const float sil = gv / (1.0f + expf(-gv));
                yrow[c] = (__bf16)(sil * acc[qs][ds][j] * rs);
            }
        }
}

// ============================================================================
// launch
// ============================================================================
extern "C" void kernel_launch(void* const* d_in, const int* in_sizes, int n_in,
                              void* d_out, int out_size, void* d_ws, size_t ws_size,
                              hipStream_t stream) {
    (void)in_sizes; (void)n_in; (void)out_size; (void)ws_size;

    const float* x    = (const float*)d_in[0];
    const float* sinT = (const float*)d_in[1];
    const float* cosT = (const float*)d_in[2];
    // d_in[3] (mask) is recomputed on the fly in retention_mfma
    const float* Wq   = (const float*)d_in[4];
    const float* Wk   = (const float*)d_in[5];
    const float* Wv   = (const float*)d_in[6];
    const float* Wg   = (const float*)d_in[7];
    const float* Wo   = (const float*)d_in[8];
    float* out = (float*)d_out;

    // workspace layout (bytes). WqT..WgT contiguous -> packed [6144][1024].
    char* wsp = (char*)d_ws;
    __bf16* xb  = (__bf16*)(wsp);
    __bf16* WqT = (__bf16*)(wsp + (8u  << 20));
    __bf16* WkT = (__bf16*)(wsp + (10u << 20));
    __bf16* WvT = (__bf16*)(wsp + (12u << 20));
    __bf16* WgT = (__bf16*)(wsp + (16u << 20));
    __bf16* WoT = (__bf16*)(wsp + (20u << 20));
    __bf16* Qb  = (__bf16*)(wsp + (24u << 20));
    __bf16* Kb  = (__bf16*)(wsp + (32u << 20));
    __bf16* Yb  = (__bf16*)(wsp + (40u << 20));  // retention output (gated)
    __bf16* Gb  = (__bf16*)(wsp + (56u << 20));
    __bf16* Vt  = (__bf16*)(wsp + (72u << 20));
    __bf16* WTall = WqT;                         // packed Q|K|V|G weights

    const dim3 blk(256);
    const dim3 tblk(32, 8);

    // ---- prep (merged transposes + x convert) ----
    prep_all<<<12288, tblk, 0, stream>>>(x, Wq, Wk, Wv, Wg, Wo,
                                         xb, WqT, WkT, WvT, WgT, WoT);

    // ---- Q|K projection (proven 2-barrier 128^2; RoPE + kscale) ----
    gemm_qk<<<512, blk, 0, stream>>>(xb, WTall, Qb, Kb, sinT, cosT);

    // ---- V|G projection (8-phase 256^2, grid = exactly 1/CU) ----
    gemm_vg<<<256, 512, 0, stream>>>(xb, WTall, Vt, Gb);

    // ---- fused retention (pipelined skeleton + 4x4 outer-product PV) ----
    retention_mfma<<<512, blk, 0, stream>>>(Qb, Kb, Vt, Gb, Yb);

    // ---- output projection ----
    gemm_wo<<<512, blk, 0, stream>>>(Yb, WoT, out);
}

// Round 20
// 168.120 us; speedup vs baseline: 2.2036x; 1.0180x over previous
//
#include <hip/hip_runtime.h>
#include <hip/hip_bf16.h>
#include <math.h>

// ---- problem constants (MultiScaleRetention, B=2,T=2048,E=1024,V=2048,H=8) ----
constexpr int T_SEQ = 2048;
constexpr int BB    = 2;
constexpr int EMBED = 1024;
constexpr int VDIM  = 2048;
constexpr int NHEADS = 8;
constexpr int KDIM  = 128;
constexpr int HDIM  = 256;
constexpr int ROWS  = BB * T_SEQ;  // 4096
constexpr float EPS = 1e-6f;

typedef float  f32x4  __attribute__((ext_vector_type(4)));
typedef __bf16 bf16x8 __attribute__((ext_vector_type(8)));
typedef __bf16 bf16x4 __attribute__((ext_vector_type(4)));

// async global->LDS, 16B per lane. LDS dest is wave-uniform base + lane*16;
// global src is per-lane.
__device__ __forceinline__ void gload16(const void* g, void* l) {
    __builtin_amdgcn_global_load_lds(
        (__attribute__((address_space(1))) void*)g,
        (__attribute__((address_space(3))) void*)l, 16, 0, 0);
}

#define WAITV(n) asm volatile("s_waitcnt vmcnt(" #n ")" ::: "memory")
#define WAITLGKM() asm volatile("s_waitcnt lgkmcnt(0)" ::: "memory")
#define BARRIER() __builtin_amdgcn_s_barrier()

// ============================================================================
// Merged prep: five W[K][N] f32 -> WT[N][K] bf16 transposes (bid < 8192)
// + x f32->bf16 convert (bid >= 8192). One launch.
// ============================================================================
__global__ __launch_bounds__(256)
void prep_all(const float* __restrict__ x, const float* __restrict__ Wq,
              const float* __restrict__ Wk, const float* __restrict__ Wv,
              const float* __restrict__ Wg, const float* __restrict__ Wo,
              __bf16* __restrict__ xb,
              __bf16* __restrict__ WqT, __bf16* __restrict__ WkT,
              __bf16* __restrict__ WvT, __bf16* __restrict__ WgT,
              __bf16* __restrict__ WoT) {
    const int bid = blockIdx.x;
    const int x_ = threadIdx.x, y_ = threadIdx.y;
    if (bid >= 8192) {
        const int i = (bid - 8192) * 256 + y_ * 32 + x_;
        float4 v = reinterpret_cast<const float4*>(x)[i];
        bf16x4 o = { (__bf16)v.x, (__bf16)v.y, (__bf16)v.z, (__bf16)v.w };
        reinterpret_cast<bf16x4*>(xb)[i] = o;
        return;
    }
    const float* W; __bf16* WT; int K, N, cx, cy;
    if (bid < 1024)      { W = Wq; WT = WqT; K = 1024; N = 1024; int rm = bid;        cx = rm & 31; cy = rm >> 5; }
    else if (bid < 2048) { W = Wk; WT = WkT; K = 1024; N = 1024; int rm = bid - 1024; cx = rm & 31; cy = rm >> 5; }
    else if (bid < 4096) { W = Wv; WT = WvT; K = 1024; N = 2048; int rm = bid - 2048; cx = rm & 63; cy = rm >> 6; }
    else if (bid < 6144) { W = Wg; WT = WgT; K = 1024; N = 2048; int rm = bid - 4096; cx = rm & 63; cy = rm >> 6; }
    else                 { W = Wo; WT = WoT; K = 2048; N = 1024; int rm = bid - 6144; cx = rm & 31; cy = rm >> 5; }

    __shared__ float tile[32][33];
    const int c0 = cx * 32, k0 = cy * 32;
    #pragma unroll
    for (int p = 0; p < 4; ++p)
        tile[y_ + p * 8][x_] = W[(size_t)(k0 + y_ + p * 8) * N + c0 + x_];
    __syncthreads();
    #pragma unroll
    for (int p = 0; p < 4; ++p)
        WT[(size_t)(c0 + y_ + p * 8) * K + k0 + x_] = (__bf16)tile[x_][y_ + p * 8];
}

// ============================================================================
// Kernel B: Q|K projection GEMM (2-barrier m97, 128x128, BK=64, G4 swizzle).
// RoPE + kscale in epilogue. Grid 512 = 2/CU; XCD col-pinning.
// ============================================================================
__global__ __launch_bounds__(256)
void gemm_qk(const __bf16* __restrict__ A, const __bf16* __restrict__ BT,
             __bf16* __restrict__ Qb, __bf16* __restrict__ Kb,
             const float* __restrict__ sinT, const float* __restrict__ cosT) {
    constexpr int K = EMBED;
    __shared__ __align__(16) char smem[32768];
    __bf16* As = (__bf16*)smem;               // [128][64] linear, swizzled
    __bf16* Bs = (__bf16*)(smem + 16384);     // [128][64] linear, swizzled

    const int bid = blockIdx.x;
    const int rr = bid >> 3;                  // 0..63
    const int bx = (bid & 7) * 2 + (rr & 1);  // 0..15 (2 cols per XCD)
    const int by = rr >> 1;                   // 0..31
    const int rowBase = by * 128;
    const int colBase = bx * 128;

    const int tid = threadIdx.x;
    const int w = tid >> 6, lane = tid & 63;
    const int g = lane >> 4, r = lane & 15;
    const int wm = w >> 1, wn = w & 1;

    const int vr  = lane >> 3;
    const int swz = ((lane & 7) ^ vr) * 8;
    const __bf16* aSb = A  + (size_t)(rowBase + 32 * w + vr) * K + swz;
    const __bf16* bSb = BT + (size_t)(colBase + 32 * w + vr) * K + swz;

    f32x4 acc[4][4];
    #pragma unroll
    for (int i = 0; i < 4; ++i)
        #pragma unroll
        for (int j = 0; j < 4; ++j)
            acc[i][j] = (f32x4){0.f, 0.f, 0.f, 0.f};

    for (int k0 = 0; k0 < K; k0 += 64) {
        __syncthreads();
        #pragma unroll
        for (int p = 0; p < 4; ++p) {
            const int cc = 4 * w + p;
            gload16(aSb + (size_t)(8 * p) * K + k0, smem         + cc * 1024);
            gload16(bSb + (size_t)(8 * p) * K + k0, smem + 16384 + cc * 1024);
        }
        __syncthreads();

        #pragma unroll
        for (int kk = 0; kk < 2; ++kk) {
            bf16x8 bfrag[4];
            #pragma unroll
            for (int nf = 0; nf < 4; ++nf) {
                const int row = wn * 64 + nf * 16 + r;
                bfrag[nf] = *reinterpret_cast<const bf16x8*>(
                    &Bs[row * 64 + (((kk << 2) + g) ^ (r & 7)) * 8]);
            }
            #pragma unroll
            for (int mf = 0; mf < 4; ++mf) {
                const int row = wm * 64 + mf * 16 + r;
                bf16x8 a = *reinterpret_cast<const bf16x8*>(
                    &As[row * 64 + (((kk << 2) + g) ^ (r & 7)) * 8]);
                #pragma unroll
                for (int nf = 0; nf < 4; ++nf)
                    acc[mf][nf] = __builtin_amdgcn_mfma_f32_16x16x32_bf16(a, bfrag[nf], acc[mf][nf], 0, 0, 0);
            }
        }
    }

    constexpr float kscale = 0.08838834764831845f;  // KEY_DIM^-0.5
    __bf16* dst; int cofs; float alphaSeg;
    if (colBase < 1024) { dst = Qb; cofs = colBase;        alphaSeg = 1.0f;   }
    else                { dst = Kb; cofs = colBase - 1024; alphaSeg = kscale; }

    #pragma unroll
    for (int mf = 0; mf < 4; ++mf)
        #pragma unroll
        for (int nf = 0; nf < 4; ++nf)
            #pragma unroll
            for (int j = 0; j < 4; ++j) {
                const int row  = rowBase + wm * 64 + mf * 16 + g * 4 + j;
                const int colL = cofs + wn * 64 + nf * 16 + r;
                float v = acc[mf][nf][j] * alphaSeg;
                const float p = __shfl_xor(v, 1);
                const int t  = row & (T_SEQ - 1);
                const int dh = colL & (KDIM - 1);
                const float c = cosT[t * KDIM + dh];
                const float s = sinT[t * KDIM + dh];
                v = (r & 1) ? (v * c + p * s) : (v * c - p * s);
                dst[(size_t)row * 1024 + colL] = (__bf16)v;
            }
}

// ============================================================================
// Kernel A: V|G projection GEMM — 256x256 8-PHASE, grid 256 = 1/CU.
// ============================================================================
#define STAGEH(ISB, TAU, HF) do { \
    const __bf16* s_ = ((ISB) ? BT : A) + \
        (size_t)((((ISB) ? colBase : rowBase)) + (HF) * 128 + w * 8 + srow) * 1024 + \
        (TAU) * 64 + swz; \
    char* d_ = smem + ((ISB) ? 65536 : 0) + (((TAU) & 1) * 2 + (HF)) * 16384 + w * 1024; \
    gload16(s_, d_); \
    gload16(s_ + (size_t)64 * 1024, d_ + 8192); \
} while (0)

#define QPHASE(TAU, Q, STGSTMT) do { \
    const int p_ = (TAU) & 1; \
    const __bf16* Ab_ = (const __bf16*)(smem + (p_ * 2 + wm) * 16384); \
    const __bf16* Bb_ = (const __bf16*)(smem + 65536 + (p_ * 2 + bh) * 16384); \
    if ((Q) == 0) { \
        _Pragma("unroll") for (int nf = 0; nf < 4; ++nf) \
        _Pragma("unroll") for (int kk = 0; kk < 2; ++kk) \
            bq[nf][kk] = *(const bf16x8*)(Bb_ + (bro + nf * 16) * 64 + ((kk * 4 + g) ^ rx) * 8); \
    } \
    bf16x8 aq_[2][2]; \
    _Pragma("unroll") for (int i = 0; i < 2; ++i) \
    _Pragma("unroll") for (int kk = 0; kk < 2; ++kk) \
        aq_[i][kk] = *(const bf16x8*)(Ab_ + (((Q) * 2 + i) * 16 + r) * 64 + ((kk * 4 + g) ^ rx) * 8); \
    STGSTMT; \
    BARRIER(); \
    __builtin_amdgcn_s_setprio(1); \
    _Pragma("unroll") for (int i = 0; i < 2; ++i) \
    _Pragma("unroll") for (int nf = 0; nf < 4; ++nf) \
    _Pragma("unroll") for (int kk = 0; kk < 2; ++kk) \
        acc[(Q) * 2 + i][nf] = __builtin_amdgcn_mfma_f32_16x16x32_bf16( \
            aq_[i][kk], bq[nf][kk], acc[(Q) * 2 + i][nf], 0, 0, 0); \
    __builtin_amdgcn_s_setprio(0); \
} while (0)

__global__ __launch_bounds__(512, 2)
void gemm_vg(const __bf16* __restrict__ A, const __bf16* __restrict__ BT,
             __bf16* __restrict__ Vt, __bf16* __restrict__ Gb) {
    __shared__ __align__(16) char smem[131072];

    const int bid = blockIdx.x;
    const int j2 = bid >> 3;                    // 0..31
    const int bxA = (bid & 7) * 2 + (j2 & 1);   // 0..15
    const int by  = j2 >> 1;                    // 0..15
    const int rowBase = by * 256;
    const int colBase = 2048 + bxA * 256;       // packed-WT row offset

    const int tid = threadIdx.x;
    const int w = tid >> 6, lane = tid & 63;
    const int g = lane >> 4, r = lane & 15;
    const int wm = w >> 2, wn = w & 3;
    const int rx = r & 7;
    const int bh = wn >> 1;
    const int bro = (wn & 1) * 64 + r;

    const int srow = lane >> 3;
    const int swz  = ((lane & 7) ^ srow) * 8;

    f32x4 acc[8][4];
    #pragma unroll
    for (int i = 0; i < 8; ++i)
        #pragma unroll
        for (int j = 0; j < 4; ++j)
            acc[i][j] = (f32x4){0.f, 0.f, 0.f, 0.f};
    bf16x8 bq[4][2];

    STAGEH(1, 0, 0); STAGEH(1, 0, 1);
    STAGEH(0, 0, 0); STAGEH(0, 0, 1);
    STAGEH(1, 1, 0); STAGEH(1, 1, 1);
    WAITV(4);
    BARRIER();

    for (int it = 0; it < 8; ++it) {
        const int e = 2 * it, o = e + 1;
        const bool more = (it < 7);
        QPHASE(e, 0, STAGEH(0, o, 0));                        BARRIER();
        QPHASE(e, 1, STAGEH(0, o, 1));                        BARRIER();
        QPHASE(e, 2, if (more) STAGEH(1, e + 2, 0));          BARRIER();
        QPHASE(e, 3, if (more) STAGEH(1, e + 2, 1));
        if (more) { WAITV(4); } else { WAITV(0); }            BARRIER();
        QPHASE(o, 0, if (more) STAGEH(0, e + 2, 0));          BARRIER();
        QPHASE(o, 1, if (more) STAGEH(0, e + 2, 1));          BARRIER();
        QPHASE(o, 2, if (more) STAGEH(1, o + 2, 0));          BARRIER();
        QPHASE(o, 3, if (more) STAGEH(1, o + 2, 1));
        if (more) { WAITV(4); } else { WAITV(0); }            BARRIER();
    }

    if (bxA < 8) {
        // V segment: transposed write to Vt[b][h][d][t]
        __bf16* Es = (__bf16*)smem + w * 4608;
        const int colV0 = (colBase - 2048) + wn * 64;
        const int h = colV0 >> 8, dd0 = colV0 & 255;
        const int li = lane & 7, rgrp = lane >> 3;
        #pragma unroll
        for (int h2 = 0; h2 < 2; ++h2) {
            #pragma unroll
            for (int mf = 0; mf < 4; ++mf)
                #pragma unroll
                for (int nf = 0; nf < 4; ++nf) {
                    f32x4 a = acc[h2 * 4 + mf][nf];
                    bf16x4 v = { (__bf16)a[0], (__bf16)a[1], (__bf16)a[2], (__bf16)a[3] };
                    *reinterpret_cast<bf16x4*>(&Es[(nf * 16 + r) * 72 + mf * 16 + g * 4]) = v;
                }
            __syncthreads();
            const int t0g = rowBase + wm * 128 + h2 * 64;
            const int bq_ = t0g >> 11, tl = t0g & 2047;
            __bf16* vtb = Vt + ((size_t)(bq_ * NHEADS + h) * HDIM + dd0) * T_SEQ + tl;
            #pragma unroll
            for (int c = 0; c < 8; ++c) {
                const int drow = 8 * c + rgrp;
                bf16x8 v = *reinterpret_cast<const bf16x8*>(&Es[drow * 72 + li * 8]);
                *reinterpret_cast<bf16x8*>(vtb + (size_t)drow * T_SEQ + li * 8) = v;
            }
            __syncthreads();
        }
        return;
    }

    const int cofs = colBase - 4096;
    #pragma unroll
    for (int mf = 0; mf < 8; ++mf)
        #pragma unroll
        for (int nf = 0; nf < 4; ++nf)
            #pragma unroll
            for (int j = 0; j < 4; ++j) {
                const int row  = rowBase + wm * 128 + mf * 16 + g * 4 + j;
                const int colL = cofs + wn * 64 + nf * 16 + r;
                Gb[(size_t)row * 2048 + colL] = (__bf16)acc[mf][nf][j];
            }
}

// ============================================================================
// Output projection: 64x128 tile, BK=64, 2-barrier, XCD swizzle.
// ============================================================================
__global__ __launch_bounds__(256)
void gemm_wo(const __bf16* __restrict__ A, const __bf16* __restrict__ BT,
             float* __restrict__ C) {
    constexpr int N = EMBED, K = VDIM;
    __shared__ __align__(16) char smem[24576];
    __bf16* As = (__bf16*)smem;               // [64][64]
    __bf16* Bs = (__bf16*)(smem + 8192);      // [128][64]

    const int bid = blockIdx.x;
    const int swzb = (bid & 7) * 64 + (bid >> 3);
    const int rowBase = (swzb >> 3) * 64;
    const int colBase = (swzb & 7) * 128;

    const int tid = threadIdx.x;
    const int w = tid >> 6, lane = tid & 63;
    const int g = lane >> 4, r = lane & 15;
    const int wm = w >> 1, wn = w & 1;

    const int vr  = lane >> 3;
    const int swz = ((lane & 7) ^ vr) * 8;
    const __bf16* aSb = A  + (size_t)(rowBase + 16 * w + vr) * K + swz;
    const __bf16* bSb = BT + (size_t)(colBase + 32 * w + vr) * K + swz;

    f32x4 acc[2][4];
    #pragma unroll
    for (int i = 0; i < 2; ++i)
        #pragma unroll
        for (int j = 0; j < 4; ++j)
            acc[i][j] = (f32x4){0.f, 0.f, 0.f, 0.f};

    for (int k0 = 0; k0 < K; k0 += 64) {
        __syncthreads();
        #pragma unroll
        for (int p = 0; p < 2; ++p) {
            const int cc = 2 * w + p;
            gload16(aSb + (size_t)(8 * p) * K + k0, smem + cc * 1024);
        }
        #pragma unroll
        for (int p = 0; p < 4; ++p) {
            const int cc = 4 * w + p;
            gload16(bSb + (size_t)(8 * p) * K + k0, smem + 8192 + cc * 1024);
        }
        __syncthreads();

        #pragma unroll
        for (int kk = 0; kk < 2; ++kk) {
            bf16x8 bfrag[4];
            #pragma unroll
            for (int nf = 0; nf < 4; ++nf) {
                const int row = wn * 64 + nf * 16 + r;
                bfrag[nf] = *reinterpret_cast<const bf16x8*>(
                    &Bs[row * 64 + (((kk << 2) + g) ^ (r & 7)) * 8]);
            }
            #pragma unroll
            for (int mf = 0; mf < 2; ++mf) {
                const int row = wm * 32 + mf * 16 + r;
                bf16x8 a = *reinterpret_cast<const bf16x8*>(
                    &As[row * 64 + (((kk << 2) + g) ^ (r & 7)) * 8]);
                #pragma unroll
                for (int nf = 0; nf < 4; ++nf)
                    acc[mf][nf] = __builtin_amdgcn_mfma_f32_16x16x32_bf16(a, bfrag[nf], acc[mf][nf], 0, 0, 0);
            }
        }
    }

    #pragma unroll
    for (int mf = 0; mf < 2; ++mf)
        #pragma unroll
        for (int nf = 0; nf < 4; ++nf)
            #pragma unroll
            for (int j = 0; j < 4; ++j) {
                const int row = rowBase + wm * 32 + mf * 16 + g * 4 + j;
                const int col = colBase + wn * 64 + nf * 16 + r;
                C[(size_t)row * N + col] = acc[mf][nf][j];
            }
}

// ============================================================================
// MFMA retention — R19 (pipelined skeleton + 4x4 outer-product PV), with
// INCREMENTAL decay factors: wj(st+1) = wj(st) * rho^-64 replaces per-tile
// exp2f (4 transcendentals/tile off the QK-entry critical path; f32 drift
// <= 32 ulp, invisible vs bf16 rounding).
// ============================================================================
__global__ __launch_bounds__(256)
void retention_mfma(const __bf16* __restrict__ Qb, const __bf16* __restrict__ Kb,
                    const __bf16* __restrict__ Vt,
                    const __bf16* __restrict__ Gb, __bf16* __restrict__ Yb) {
    const int tid = threadIdx.x;
    const int w = tid >> 6, lane = tid & 63;
    const int g = lane >> 4, r = lane & 15;
    const int rx = r & 7;
    const int bid = blockIdx.x;
    const int h = bid & 7;
    const int slot = bid >> 3;
    const int b = slot & 1;
    const int x = slot >> 1;
    const int qt = (b == 0) ? (31 - x) : x;
    const int tt0 = qt * 64;
    const int trow0 = w * 16;

    __shared__ __align__(16) __bf16 Ks[2][64][128];
    __shared__ __align__(16) __bf16 Vs[256][64];
    __shared__ __align__(16) __bf16 Ps[64][72];   // SHARED P tile, +8 pad
    __shared__ float dsumL[64];
    __shared__ float ssL[4][64];

    const float rho   = 1.0f - exp2f(-(float)(5 + h));
    const float l2r   = log2f(rho);
    const float inv1m = exp2f((float)(5 + h));
    int   tj[4];
    float wjr[4];                                  // running rho^(tj-ss0)*nrm
    #pragma unroll
    for (int j = 0; j < 4; ++j) {
        tj[j] = tt0 + trow0 + g * 4 + j;
        const float nrm = rsqrtf((1.0f - exp2f(l2r * (float)(tj[j] + 1))) * inv1m);
        wjr[j] = exp2f(l2r * (float)tj[j]) * nrm;  // st=0 value
    }
    const float rstep = exp2f(-64.0f * l2r);       // rho^-64 per-tile growth
    float pneg[4];
    #pragma unroll
    for (int ssub = 0; ssub < 4; ++ssub)
        pneg[ssub] = exp2f(-l2r * (float)(ssub * 16 + r));

    bf16x8 qf[4];
    {
        const __bf16* qrow = Qb + ((size_t)(b * T_SEQ + tt0 + trow0 + r)) * EMBED + h * KDIM;
        #pragma unroll
        for (int kb = 0; kb < 4; ++kb)
            qf[kb] = *reinterpret_cast<const bf16x8*>(qrow + kb * 32 + g * 8);
    }

    // PV accumulator: [qsub][dsub] -> q = qsub*16+g*4+j, d = w*64+dsub*16+r
    f32x4 acc[4][4];
    #pragma unroll
    for (int qs = 0; qs < 4; ++qs)
        #pragma unroll
        for (int ds = 0; ds < 4; ++ds)
            acc[qs][ds] = (f32x4){0.f, 0.f, 0.f, 0.f};
    float dsum[4] = {0.f, 0.f, 0.f, 0.f};

    const __bf16* vtbase = Vt + ((size_t)(b * NHEADS + h) * HDIM) * T_SEQ;
    const __bf16* kbase  = Kb + ((size_t)(b * T_SEQ)) * EMBED + h * KDIM;

    const int klr = lane >> 4;
    const int kc  = lane & 15;
    const int kswz_even = (kc ^ klr) * 8;
    const int kswz_odd  = (kc ^ (4 + klr)) * 8;
    const int vlr  = lane >> 3;
    const int vswz = ((lane & 7) ^ vlr) * 8;

    #pragma unroll
    for (int p = 0; p < 4; ++p) {
        const int cc = 4 * w + p;
        const int se = (p & 1) ? kswz_odd : kswz_even;
        gload16(kbase + (size_t)(4 * cc + klr) * EMBED + se,
                (char*)&Ks[0][0][0] + cc * 1024);
    }

    int cur = 0;
    const int nS = qt + 1;
    for (int st = 0; st < nS; ++st) {
        const int ss0 = st * 64;
        WAITV(0);
        BARRIER();   // K(st) visible; prev PV's Ps/Vs reads all consumed

        #pragma unroll
        for (int p = 0; p < 8; ++p) {
            const int cc = 8 * w + p;
            gload16(vtbase + (size_t)(8 * cc + vlr) * T_SEQ + ss0 + vswz,
                    (char*)&Vs[0][0] + cc * 1024);
        }
        const bool more = (st + 1 < nS);
        if (more) {
            const int ssn = ss0 + 64;
            #pragma unroll
            for (int p = 0; p < 4; ++p) {
                const int cc = 4 * w + p;
                const int se = (p & 1) ? kswz_odd : kswz_even;
                gload16(kbase + (size_t)(ssn + 4 * cc + klr) * EMBED + se,
                        (char*)&Ks[cur ^ 1][0][0] + cc * 1024);
            }
        }

        const bool diag = (st == qt);

        // ---- QK^T (own 16 q-rows x all 64 s) -> SHARED Ps ----
        __builtin_amdgcn_s_setprio(1);
        #pragma unroll
        for (int ssub = 0; ssub < 4; ++ssub) {
            f32x4 sacc = (f32x4){0.f, 0.f, 0.f, 0.f};
            #pragma unroll
            for (int kb = 0; kb < 4; ++kb) {
                bf16x8 kf = *reinterpret_cast<const bf16x8*>(
                    &Ks[cur][ssub * 16 + r][((kb * 4 + g) ^ rx) * 8]);
                sacc = __builtin_amdgcn_mfma_f32_16x16x32_bf16(qf[kb], kf, sacc, 0, 0, 0);
            }
            const int scol = ss0 + ssub * 16 + r;
            const float mfac = pneg[ssub];
            #pragma unroll
            for (int j = 0; j < 4; ++j) {
                float pv = sacc[j] * (wjr[j] * mfac);
                if (diag && scol > tj[j]) pv = 0.f;
                dsum[j] += fabsf(pv);
                Ps[trow0 + g * 4 + j][ssub * 16 + r] = (__bf16)pv;
            }
        }
        __builtin_amdgcn_s_setprio(0);
        #pragma unroll
        for (int j = 0; j < 4; ++j) wjr[j] *= rstep;  // advance decay

        if (more) { WAITV(4); } else { WAITV(0); }
        WAITLGKM();   // drain Ps ds_writes (cross-wave visibility)
        BARRIER();    // all waves: Ps(st) + Vs(st) visible

        // ---- PV 4x4: wave w owns d-cols [64w,64w+64) x all 64 q ----
        __builtin_amdgcn_s_setprio(1);
        #pragma unroll
        for (int sh = 0; sh < 2; ++sh) {
            bf16x8 pf[4];
            #pragma unroll
            for (int qs = 0; qs < 4; ++qs)
                pf[qs] = *reinterpret_cast<const bf16x8*>(
                    &Ps[qs * 16 + r][sh * 32 + g * 8]);
            #pragma unroll
            for (int ds = 0; ds < 4; ++ds) {
                bf16x8 vf = *reinterpret_cast<const bf16x8*>(
                    &Vs[w * 64 + ds * 16 + r][((sh * 4 + g) ^ rx) * 8]);
                #pragma unroll
                for (int qs = 0; qs < 4; ++qs)
                    acc[qs][ds] = __builtin_amdgcn_mfma_f32_16x16x32_bf16(pf[qs], vf, acc[qs][ds], 0, 0, 0);
            }
        }
        __builtin_amdgcn_s_setprio(0);
        cur ^= 1;
    }

    // ---- epilogue (cross-wave reduction) ----
    #pragma unroll
    for (int j = 0; j < 4; ++j) {
        float v = dsum[j];
        v += __shfl_xor(v, 1); v += __shfl_xor(v, 2);
        v += __shfl_xor(v, 4); v += __shfl_xor(v, 8);
        dsum[j] = fminf(fmaxf(v, 1.0f), 50000.0f);
    }
    if (r == 0) {
        #pragma unroll
        for (int j = 0; j < 4; ++j)
            dsumL[trow0 + g * 4 + j] = dsum[j];
    }
    __syncthreads();

    #pragma unroll
    for (int qs = 0; qs < 4; ++qs)
        #pragma unroll
        for (int j = 0; j < 4; ++j) {
            const float inv = 1.0f / dsumL[qs * 16 + g * 4 + j];
            float sp = 0.f;
            #pragma unroll
            for (int ds = 0; ds < 4; ++ds) {
                const float v = acc[qs][ds][j] * inv;
                acc[qs][ds][j] = v;
                sp = fmaf(v, v, sp);
            }
            sp += __shfl_xor(sp, 1); sp += __shfl_xor(sp, 2);
            sp += __shfl_xor(sp, 4); sp += __shfl_xor(sp, 8);
            if (r == 0) ssL[w][qs * 16 + g * 4 + j] = sp;
        }
    __syncthreads();

    #pragma unroll
    for (int qs = 0; qs < 4; ++qs)
        #pragma unroll
        for (int j = 0; j < 4; ++j) {
            const int ql = qs * 16 + g * 4 + j;
            const float tot = ssL[0][ql] + ssL[1][ql] + ssL[2][ql] + ssL[3][ql];
            const float rs = rsqrtf(tot * (1.0f / 256.0f) + EPS);
            const size_t row = (size_t)(b * T_SEQ + tt0 + ql);
            const __bf16* grow = Gb + row * VDIM + h * HDIM;
            __bf16* yrow = Yb + row * VDIM + h * HDIM;
            #pragma unroll
            for (int ds = 0; ds < 4; ++ds) {
                const int c = w * 64 + ds * 16 + r;
                const float gv = (float)grow[c];
                const float sil = gv / (1.0f + expf(-gv));
                yrow[c] = (__bf16)(sil * acc[qs][ds][j] * rs);
            }
        }
}

// ============================================================================
// launch
// ============================================================================
extern "C" void kernel_launch(void* const* d_in, const int* in_sizes, int n_in,
                              void* d_out, int out_size, void* d_ws, size_t ws_size,
                              hipStream_t stream) {
    (void)in_sizes; (void)n_in; (void)out_size; (void)ws_size;

    const float* x    = (const float*)d_in[0];
    const float* sinT = (const float*)d_in[1];
    const float* cosT = (const float*)d_in[2];
    // d_in[3] (mask) is recomputed on the fly in retention_mfma
    const float* Wq   = (const float*)d_in[4];
    const float* Wk   = (const float*)d_in[5];
    const float* Wv   = (const float*)d_in[6];
    const float* Wg   = (const float*)d_in[7];
    const float* Wo   = (const float*)d_in[8];
    float* out = (float*)d_out;

    // workspace layout (bytes). WqT..WgT contiguous -> packed [6144][1024].
    char* wsp = (char*)d_ws;
    __bf16* xb  = (__bf16*)(wsp);
    __bf16* WqT = (__bf16*)(wsp + (8u  << 20));
    __bf16* WkT = (__bf16*)(wsp + (10u << 20));
    __bf16* WvT = (__bf16*)(wsp + (12u << 20));
    __bf16* WgT = (__bf16*)(wsp + (16u << 20));
    __bf16* WoT = (__bf16*)(wsp + (20u << 20));
    __bf16* Qb  = (__bf16*)(wsp + (24u << 20));
    __bf16* Kb  = (__bf16*)(wsp + (32u << 20));
    __bf16* Yb  = (__bf16*)(wsp + (40u << 20));  // retention output (gated)
    __bf16* Gb  = (__bf16*)(wsp + (56u << 20));
    __bf16* Vt  = (__bf16*)(wsp + (72u << 20));
    __bf16* WTall = WqT;                         // packed Q|K|V|G weights

    const dim3 blk(256);
    const dim3 tblk(32, 8);

    // ---- prep (merged transposes + x convert) ----
    prep_all<<<12288, tblk, 0, stream>>>(x, Wq, Wk, Wv, Wg, Wo,
                                         xb, WqT, WkT, WvT, WgT, WoT);

    // ---- Q|K projection (proven 2-barrier 128^2; RoPE + kscale) ----
    gemm_qk<<<512, blk, 0, stream>>>(xb, WTall, Qb, Kb, sinT, cosT);

    // ---- V|G projection (8-phase 256^2, grid = exactly 1/CU) ----
    gemm_vg<<<256, 512, 0, stream>>>(xb, WTall, Vt, Gb);

    // ---- fused retention (pipelined + 4x4 PV + incremental decay) ----
    retention_mfma<<<512, blk, 0, stream>>>(Qb, Kb, Vt, Gb, Yb);

    // ---- output projection ----
    gemm_wo<<<512, blk, 0, stream>>>(Yb, WoT, out);
}